// Round 2
// baseline (9606.205 us; speedup 1.0000x reference)
//
#include <hip/hip_runtime.h>
#include <hip/hip_bf16.h>
#include <math.h>

// ---------------- problem constants ----------------
#define BB 64
#define HH 14
#define WW 14
#define CC 1024
#define WS 7
#define SHIFT 3
#define NH 32
#define HD 32
#define NTOK (BB * HH * WW)      // 12544
#define SCALE 0.17677669529663687f  // 32^-0.5

// ---------------- static device workspace (bypasses d_ws entirely) ----------
__device__ __align__(16) float g_X [(size_t)NTOK * CC];     // residual state
__device__ __align__(16) float g_B2[(size_t)NTOK * CC];     // LN out / attn out
__device__ __align__(16) float g_B1[(size_t)NTOK * 4096];   // QKV / FC1 out
__device__ __align__(16) float g_H0[64 * CC];
__device__ __align__(16) float g_H1[64 * 512];
__device__ __align__(16) float g_H2[64 * 128];

__device__ __forceinline__ float gelu_f(float x) {
    return 0.5f * x * (1.0f + erff(x * 0.70710678118654752f));
}

// window-order row r (bn*49+t) -> row in X ([B,14,14] flattened), matching
// window_partition(roll(h,-3,-3)) gather / its inverse scatter.
__device__ __forceinline__ int win_to_xrow(int r, int shifted) {
    int bn = r / 49, t = r - bn * 49;
    int b = bn >> 2, w = bn & 3;
    int wh = w >> 1, ww_ = w & 1;
    int th = t / 7, tw = t - th * 7;
    int gh = wh * 7 + th, gw = ww_ * 7 + tw;
    if (shifted) { gh = gh + 3; if (gh >= 14) gh -= 14; gw = gw + 3; if (gw >= 14) gw -= 14; }
    return b * 196 + gh * 14 + gw;
}

// ---------------- LayerNorm (optionally fused with window partition+shift) ----
// one wave (64 lanes) per output token; 4 waves per block
__global__ __launch_bounds__(256) void ln_kernel(const float* __restrict__ X,
    const float* __restrict__ g, const float* __restrict__ bta,
    float* __restrict__ out, int shifted, int partition)
{
    int token = blockIdx.x * 4 + (threadIdx.x >> 6);
    int lane = threadIdx.x & 63;
    int xrow = partition ? win_to_xrow(token, shifted) : token;
    const float4* src = (const float4*)(X + (size_t)xrow * CC);
    float4 v[4];
    float s = 0.f;
    #pragma unroll
    for (int w = 0; w < 4; ++w) {
        v[w] = src[w * 64 + lane];
        s += v[w].x + v[w].y + v[w].z + v[w].w;
    }
    #pragma unroll
    for (int o = 32; o; o >>= 1) s += __shfl_xor(s, o);
    float mean = s * (1.0f / CC);
    float ss = 0.f;
    #pragma unroll
    for (int w = 0; w < 4; ++w) {
        float d0 = v[w].x - mean, d1 = v[w].y - mean, d2 = v[w].z - mean, d3 = v[w].w - mean;
        ss += d0 * d0 + d1 * d1 + d2 * d2 + d3 * d3;
    }
    #pragma unroll
    for (int o = 32; o; o >>= 1) ss += __shfl_xor(ss, o);
    float inv = 1.0f / sqrtf(ss * (1.0f / CC) + 1e-5f);
    float4* dst = (float4*)(out + (size_t)token * CC);
    #pragma unroll
    for (int w = 0; w < 4; ++w) {
        int c4 = w * 64 + lane;
        float4 gv = *(const float4*)(g + c4 * 4);
        float4 bv = *(const float4*)(bta + c4 * 4);
        float4 o4;
        o4.x = (v[w].x - mean) * inv * gv.x + bv.x;
        o4.y = (v[w].y - mean) * inv * gv.y + bv.y;
        o4.z = (v[w].z - mean) * inv * gv.z + bv.z;
        o4.w = (v[w].w - mean) * inv * gv.w + bv.w;
        dst[c4] = o4;
    }
}

// ---------------- fp32 GEMM, 128x128 tile, 16 k-step, 256 threads, 8x8 micro --
// EPI: 0 = store, 1 = store+gelu, 2 = residual-add into X via window map,
//      3 = residual-add into X direct rows
template<int EPI>
__global__ __launch_bounds__(256) void gemm128(const float* __restrict__ A,
    const float* __restrict__ W, const float* __restrict__ bias,
    float* __restrict__ Cout, int M, int N, int K, int shifted)
{
    __shared__ float As[16][128];
    __shared__ float Ws[16][128];
    const int tid = threadIdx.x;
    const int row0 = blockIdx.y * 128, col0 = blockIdx.x * 128;
    const int ty = tid >> 4, tx = tid & 15;
    float acc[8][8] = {};
    for (int k0 = 0; k0 < K; k0 += 16) {
        #pragma unroll
        for (int l = 0; l < 2; ++l) {
            int f = l * 256 + tid;
            // A tile: 128 rows x 16 cols
            int ar = f >> 2, akq = f & 3;
            float4 av = *(const float4*)(A + (size_t)(row0 + ar) * K + k0 + akq * 4);
            As[akq * 4 + 0][ar] = av.x;
            As[akq * 4 + 1][ar] = av.y;
            As[akq * 4 + 2][ar] = av.z;
            As[akq * 4 + 3][ar] = av.w;
            // W tile: 16 rows x 128 cols
            int wk = f >> 5, wc = f & 31;
            *(float4*)(&Ws[wk][wc * 4]) =
                *(const float4*)(W + (size_t)(k0 + wk) * N + col0 + wc * 4);
        }
        __syncthreads();
        #pragma unroll
        for (int kk = 0; kk < 16; ++kk) {
            float a[8], w[8];
            *(float4*)(a)     = *(const float4*)(&As[kk][ty * 8]);
            *(float4*)(a + 4) = *(const float4*)(&As[kk][ty * 8 + 4]);
            *(float4*)(w)     = *(const float4*)(&Ws[kk][tx * 8]);
            *(float4*)(w + 4) = *(const float4*)(&Ws[kk][tx * 8 + 4]);
            #pragma unroll
            for (int i = 0; i < 8; ++i)
                #pragma unroll
                for (int j = 0; j < 8; ++j)
                    acc[i][j] = fmaf(a[i], w[j], acc[i][j]);
        }
        __syncthreads();
    }
    #pragma unroll
    for (int i = 0; i < 8; ++i) {
        int r = row0 + ty * 8 + i;
        int orow = (EPI == 2) ? win_to_xrow(r, shifted) : r;
        #pragma unroll
        for (int j = 0; j < 8; ++j) {
            int c = col0 + tx * 8 + j;
            float v = acc[i][j] + bias[c];
            if (EPI == 1) v = gelu_f(v);
            if (EPI == 0 || EPI == 1) {
                Cout[(size_t)r * N + c] = v;
            } else {
                Cout[(size_t)orow * N + c] += v;
            }
        }
    }
}

// ---------------- windowed attention: one 64-lane block per (window, head) ----
__global__ __launch_bounds__(64) void attn_kernel(const float* __restrict__ qkv,
    float* __restrict__ o, const float* __restrict__ rpb, int shifted)
{
    int bh = blockIdx.x;
    int bn = bh >> 5, h = bh & 31;
    __shared__ float qs[49][32], ks[49][32], vs[49][32];
    __shared__ float ss[49][50];
    int lane = threadIdx.x;
    for (int idx = lane; idx < 49 * 32; idx += 64) {
        int t = idx >> 5, d = idx & 31;
        const float* p = qkv + (size_t)(bn * 49 + t) * 3072 + h * 32 + d;
        qs[t][d] = p[0];
        ks[t][d] = p[1024];
        vs[t][d] = p[2048];
    }
    __syncthreads();
    if (lane < 49) {
        int i = lane;
        int ih = i / 7, iw = i - ih * 7;
        int w = bn & 3, wh = w >> 1, ww_ = w & 1;
        int gh = wh * 7 + ih, gw = ww_ * 7 + iw;
        int li = (gh < 7 ? 0 : (gh < 11 ? 1 : 2)) * 3 + (gw < 7 ? 0 : (gw < 11 ? 1 : 2));
        float qreg[32];
        #pragma unroll
        for (int d = 0; d < 32; ++d) qreg[d] = qs[i][d] * SCALE;
        float mx = -1e30f;
        for (int j = 0; j < 49; ++j) {
            int jh = j / 7, jw = j - jh * 7;
            float dot = 0.f;
            #pragma unroll
            for (int d = 0; d < 32; ++d) dot = fmaf(qreg[d], ks[j][d], dot);
            int ridx = (ih - jh + 6) * 13 + (iw - jw + 6);
            float val = dot + rpb[ridx * 32 + h];
            if (shifted) {
                int gjh = wh * 7 + jh, gjw = ww_ * 7 + jw;
                int lj = (gjh < 7 ? 0 : (gjh < 11 ? 1 : 2)) * 3 +
                         (gjw < 7 ? 0 : (gjw < 11 ? 1 : 2));
                if (li != lj) val -= 100.0f;
            }
            ss[i][j] = val;
            mx = fmaxf(mx, val);
        }
        float denom = 0.f;
        for (int j = 0; j < 49; ++j) {
            float e = expf(ss[i][j] - mx);
            ss[i][j] = e;
            denom += e;
        }
        float rd = 1.0f / denom;
        float* orow = o + (size_t)(bn * 49 + i) * CC + h * 32;
        #pragma unroll 4
        for (int d = 0; d < 32; ++d) {
            float acc = 0.f;
            for (int j = 0; j < 49; ++j) acc = fmaf(ss[i][j], vs[j][d], acc);
            orow[d] = acc * rd;
        }
    }
}

// ---------------- global-avg-pool over 196 tokens + LayerNorm ----------------
__global__ __launch_bounds__(256) void pool_ln_kernel(const float* __restrict__ X,
    const float* __restrict__ g, const float* __restrict__ bta, float* __restrict__ out)
{
    int b = blockIdx.x, tid = threadIdx.x;
    int lane = tid & 63, wid = tid >> 6;
    const float* base = X + (size_t)b * 196 * CC + tid * 4;
    float a0 = 0, a1 = 0, a2 = 0, a3 = 0;
    for (int t = 0; t < 196; ++t) {
        float4 v = *(const float4*)(base + (size_t)t * CC);
        a0 += v.x; a1 += v.y; a2 += v.z; a3 += v.w;
    }
    const float inv196 = 1.0f / 196.0f;
    float p0 = a0 * inv196, p1 = a1 * inv196, p2 = a2 * inv196, p3 = a3 * inv196;
    float s = p0 + p1 + p2 + p3;
    #pragma unroll
    for (int o = 32; o; o >>= 1) s += __shfl_xor(s, o);
    __shared__ float sred[4], ssred[4];
    if (lane == 0) sred[wid] = s;
    __syncthreads();
    float mean = (sred[0] + sred[1] + sred[2] + sred[3]) * (1.0f / CC);
    float d0 = p0 - mean, d1 = p1 - mean, d2 = p2 - mean, d3 = p3 - mean;
    float ss = d0 * d0 + d1 * d1 + d2 * d2 + d3 * d3;
    #pragma unroll
    for (int o = 32; o; o >>= 1) ss += __shfl_xor(ss, o);
    if (lane == 0) ssred[wid] = ss;
    __syncthreads();
    float var = (ssred[0] + ssred[1] + ssred[2] + ssred[3]) * (1.0f / CC);
    float inv = 1.0f / sqrtf(var + 1e-5f);
    float4 gv = *(const float4*)(g + tid * 4);
    float4 bv = *(const float4*)(bta + tid * 4);
    float4 o4;
    o4.x = d0 * inv * gv.x + bv.x;
    o4.y = d1 * inv * gv.y + bv.y;
    o4.z = d2 * inv * gv.z + bv.z;
    o4.w = d3 * inv * gv.w + bv.w;
    *(float4*)(out + (size_t)b * CC + tid * 4) = o4;
}

// ---------------- tiny head GEMM: one thread per output element --------------
__global__ void head_gemm_kernel(const float* __restrict__ A, const float* __restrict__ W,
    const float* __restrict__ bias, float* __restrict__ out, int M, int K, int N, int act)
{
    int idx = blockIdx.x * blockDim.x + threadIdx.x;
    if (idx >= M * N) return;
    int r = idx / N, c = idx - r * N;
    float s = bias[c];
    for (int k = 0; k < K; ++k) s = fmaf(A[(size_t)r * K + k], W[(size_t)k * N + c], s);
    if (act) s = gelu_f(s);
    out[idx] = s;
}

// ---------------- launch ------------------------------------------------------
extern "C" void kernel_launch(void* const* d_in, const int* in_sizes, int n_in,
                              void* d_out, int out_size, void* d_ws, size_t ws_size,
                              hipStream_t stream) {
    const float* x = (const float*)d_in[0];
    auto P = [&](int i) { return (const float*)d_in[i]; };

    // resolve static device buffers (pure lookups; graph-capture-safe)
    float *X, *B2, *B1, *H0, *H1, *H2;
    { void* p;
      hipGetSymbolAddress(&p, HIP_SYMBOL(g_X));  X  = (float*)p;
      hipGetSymbolAddress(&p, HIP_SYMBOL(g_B2)); B2 = (float*)p;
      hipGetSymbolAddress(&p, HIP_SYMBOL(g_B1)); B1 = (float*)p;
      hipGetSymbolAddress(&p, HIP_SYMBOL(g_H0)); H0 = (float*)p;
      hipGetSymbolAddress(&p, HIP_SYMBOL(g_H1)); H1 = (float*)p;
      hipGetSymbolAddress(&p, HIP_SYMBOL(g_H2)); H2 = (float*)p;
    }

    hipMemcpyAsync(X, x, (size_t)NTOK * CC * sizeof(float),
                   hipMemcpyDeviceToDevice, stream);

    for (int blk = 0; blk < 2; ++blk) {
        int base = 1 + blk * 13;
        const float *ln1g = P(base + 0), *ln1b = P(base + 1);
        const float *qkvw = P(base + 2), *qkvb = P(base + 3);
        const float *rpb  = P(base + 4);
        const float *projw = P(base + 5), *projb = P(base + 6);
        const float *ln2g = P(base + 7), *ln2b = P(base + 8);
        const float *fc1w = P(base + 9), *fc1b = P(base + 10);
        const float *fc2w = P(base + 11), *fc2b = P(base + 12);
        int shifted = blk;  // block 1 is the shifted block

        // LN1 + window partition (+shift): X -> B2 [12544,1024] in window order
        ln_kernel<<<NTOK / 4, 256, 0, stream>>>(X, ln1g, ln1b, B2, shifted, 1);
        // QKV: B2 @ qkv_w -> B1 [12544,3072]
        gemm128<0><<<dim3(3072 / 128, NTOK / 128), 256, 0, stream>>>(
            B2, qkvw, qkvb, B1, NTOK, 3072, 1024, 0);
        // attention per (window, head): B1 -> B2 [12544,1024] (o, window order)
        attn_kernel<<<256 * NH, 64, 0, stream>>>(B1, B2, rpb, shifted);
        // proj + window-reverse (+unshift) + residual add into X
        gemm128<2><<<dim3(1024 / 128, NTOK / 128), 256, 0, stream>>>(
            B2, projw, projb, X, NTOK, 1024, 1024, shifted);
        // LN2: X -> B2
        ln_kernel<<<NTOK / 4, 256, 0, stream>>>(X, ln2g, ln2b, B2, 0, 0);
        // FC1 + gelu: B2 -> B1 [12544,4096]
        gemm128<1><<<dim3(4096 / 128, NTOK / 128), 256, 0, stream>>>(
            B2, fc1w, fc1b, B1, NTOK, 4096, 1024, 0);
        // FC2 + residual add into X
        gemm128<3><<<dim3(1024 / 128, NTOK / 128), 256, 0, stream>>>(
            B1, fc2w, fc2b, X, NTOK, 1024, 4096, 0);
    }

    // head: pool + LN -> H0 [64,1024]
    pool_ln_kernel<<<64, 256, 0, stream>>>(X, P(27), P(28), H0);
    head_gemm_kernel<<<(64 * 512 + 255) / 256, 256, 0, stream>>>(
        H0, P(29), P(30), H1, 64, 1024, 512, 1);
    head_gemm_kernel<<<(64 * 128 + 255) / 256, 256, 0, stream>>>(
        H1, P(31), P(32), H2, 64, 512, 128, 1);
    head_gemm_kernel<<<1, 128, 0, stream>>>(
        H2, P(33), P(34), (float*)d_out, 64, 128, 2, 0);
}

// Round 3
// 4190.870 us; speedup vs baseline: 2.2922x; 2.2922x over previous
//
#include <hip/hip_runtime.h>
#include <hip/hip_bf16.h>
#include <math.h>

// ---------------- problem constants ----------------
#define BB 64
#define CC 1024
#define NH 32
#define NTOK (BB * 14 * 14)      // 12544
#define SCALE 0.17677669529663687f  // 32^-0.5

typedef __attribute__((ext_vector_type(8))) short short8;
typedef __attribute__((ext_vector_type(4))) float f32x4;

// ---------------- static device workspace ----------------
__device__ __align__(16) float  g_X  [(size_t)NTOK * CC];        // residual (fp32)
__device__ __align__(16) float  g_QKV[(size_t)NTOK * 3072];      // qkv out (fp32)
__device__ __align__(16) unsigned short g_Bh[(size_t)NTOK * CC];  // 1024-wide act hi
__device__ __align__(16) unsigned short g_Bl[(size_t)NTOK * CC];  // 1024-wide act lo
__device__ __align__(16) unsigned short g_Ch[(size_t)NTOK * 4096];// fc1 out hi
__device__ __align__(16) unsigned short g_Cl[(size_t)NTOK * 4096];// fc1 out lo
// transposed bf16 weights [N][K], hi/lo, 2 blocks
__device__ __align__(16) unsigned short g_Wqkv_h[(size_t)2*3072*1024], g_Wqkv_l[(size_t)2*3072*1024];
__device__ __align__(16) unsigned short g_Wproj_h[(size_t)2*1024*1024], g_Wproj_l[(size_t)2*1024*1024];
__device__ __align__(16) unsigned short g_Wfc1_h[(size_t)2*4096*1024], g_Wfc1_l[(size_t)2*4096*1024];
__device__ __align__(16) unsigned short g_Wfc2_h[(size_t)2*1024*4096], g_Wfc2_l[(size_t)2*1024*4096];
__device__ __align__(16) float g_H0[64 * CC];
__device__ __align__(16) float g_H1[64 * 512];
__device__ __align__(16) float g_H2[64 * 128];

__device__ __forceinline__ float gelu_f(float x) {
    return 0.5f * x * (1.0f + erff(x * 0.70710678118654752f));
}

__device__ __forceinline__ void split_bf16(float v, unsigned short& h, unsigned short& l) {
    __hip_bfloat16 hb = __float2bfloat16(v);
    float hf = __bfloat162float(hb);
    __hip_bfloat16 lb = __float2bfloat16(v - hf);
    h = *(unsigned short*)&hb;
    l = *(unsigned short*)&lb;
}

// window-order row r (bn*49+t) -> row in X ([B,14,14] flattened)
__device__ __forceinline__ int win_to_xrow(int r, int shifted) {
    int bn = r / 49, t = r - bn * 49;
    int b = bn >> 2, w = bn & 3;
    int wh = w >> 1, ww_ = w & 1;
    int th = t / 7, tw = t - th * 7;
    int gh = wh * 7 + th, gw = ww_ * 7 + tw;
    if (shifted) { gh = gh + 3; if (gh >= 14) gh -= 14; gw = gw + 3; if (gw >= 14) gw -= 14; }
    return b * 196 + gh * 14 + gw;
}

__device__ __forceinline__ void gload_lds16(const void* g, void* l) {
    __builtin_amdgcn_global_load_lds(
        (const __attribute__((address_space(1))) unsigned int*)g,
        (__attribute__((address_space(3))) unsigned int*)l, 16, 0, 0);
}

// ---------------- weight convert + transpose: W[K][N] fp32 -> WT[N][K] bf16 hi/lo
__global__ __launch_bounds__(256) void convw_kernel(const float* __restrict__ W,
    unsigned short* __restrict__ Wh, unsigned short* __restrict__ Wl, int K, int N)
{
    __shared__ float t[32][33];
    int n0 = blockIdx.x * 32, k0 = blockIdx.y * 32;
    int tx = threadIdx.x & 31, ty = threadIdx.x >> 5;
    #pragma unroll
    for (int i = 0; i < 4; ++i)
        t[ty + 8 * i][tx] = W[(size_t)(k0 + ty + 8 * i) * N + n0 + tx];
    __syncthreads();
    #pragma unroll
    for (int i = 0; i < 4; ++i) {
        int n = ty + 8 * i;
        float v = t[tx][n];                 // W[k0+tx][n0+n]
        unsigned short h, l;
        split_bf16(v, h, l);
        size_t o = (size_t)(n0 + n) * K + k0 + tx;
        Wh[o] = h; Wl[o] = l;
    }
}

// ---------------- LayerNorm -> bf16 hi/lo (optional window partition+shift) ---
__global__ __launch_bounds__(256) void ln_kernel(const float* __restrict__ X,
    const float* __restrict__ g, const float* __restrict__ bta,
    unsigned short* __restrict__ outh, unsigned short* __restrict__ outl,
    int shifted, int partition)
{
    int token = blockIdx.x * 4 + (threadIdx.x >> 6);
    int lane = threadIdx.x & 63;
    int xrow = partition ? win_to_xrow(token, shifted) : token;
    const float4* src = (const float4*)(X + (size_t)xrow * CC);
    float4 v[4];
    float s = 0.f;
    #pragma unroll
    for (int w = 0; w < 4; ++w) {
        v[w] = src[w * 64 + lane];
        s += v[w].x + v[w].y + v[w].z + v[w].w;
    }
    #pragma unroll
    for (int o = 32; o; o >>= 1) s += __shfl_xor(s, o);
    float mean = s * (1.0f / CC);
    float ss = 0.f;
    #pragma unroll
    for (int w = 0; w < 4; ++w) {
        float d0 = v[w].x - mean, d1 = v[w].y - mean, d2 = v[w].z - mean, d3 = v[w].w - mean;
        ss += d0 * d0 + d1 * d1 + d2 * d2 + d3 * d3;
    }
    #pragma unroll
    for (int o = 32; o; o >>= 1) ss += __shfl_xor(ss, o);
    float inv = 1.0f / sqrtf(ss * (1.0f / CC) + 1e-5f);
    #pragma unroll
    for (int w = 0; w < 4; ++w) {
        int c4 = w * 64 + lane;
        float4 gv = *(const float4*)(g + c4 * 4);
        float4 bv = *(const float4*)(bta + c4 * 4);
        float o0 = (v[w].x - mean) * inv * gv.x + bv.x;
        float o1 = (v[w].y - mean) * inv * gv.y + bv.y;
        float o2 = (v[w].z - mean) * inv * gv.z + bv.z;
        float o3 = (v[w].w - mean) * inv * gv.w + bv.w;
        ushort4 uh, ul;
        split_bf16(o0, uh.x, ul.x); split_bf16(o1, uh.y, ul.y);
        split_bf16(o2, uh.z, ul.z); split_bf16(o3, uh.w, ul.w);
        *(ushort4*)(outh + (size_t)token * CC + c4 * 4) = uh;
        *(ushort4*)(outl + (size_t)token * CC + c4 * 4) = ul;
    }
}

// ---------------- bf16x3 MFMA GEMM: C = A[M][K] * WT[N][K]^T --------------
// 128x128 tile, BK=32, 4 waves (2x2), 4x4 16x16x32 frags per wave, 48 MFMA/K-step
// EPI: 0 fp32 store+bias (QKV); 1 gelu -> bf16 hi/lo store (FC1);
//      2 residual += into X via window map (proj); 3 residual += direct (FC2)
template<int EPI>
__global__ __launch_bounds__(256, 2) void gemm_mfma(
    const unsigned short* __restrict__ Ah, const unsigned short* __restrict__ Al,
    const unsigned short* __restrict__ Wh, const unsigned short* __restrict__ Wl,
    const float* __restrict__ bias,
    float* __restrict__ outf, unsigned short* __restrict__ outh,
    unsigned short* __restrict__ outl, int N, int K, int shifted)
{
    __shared__ unsigned short sm[16384];   // 4 tiles x [128][32] bf16, 8KB each
    const int tid = threadIdx.x;
    const int wave = tid >> 6, lane = tid & 63;
    const int wr = wave >> 1, wc = wave & 1;
    const int row0 = blockIdx.y * 128, col0 = blockIdx.x * 128;
    const int rsel = lane & 15, kc = lane >> 4;

    f32x4 acc[4][4] = {};

    for (int k0 = 0; k0 < K; k0 += 32) {
        // ---- stage 4 tiles (Ah,Al,Wh,Wl) via global_load_lds, swizzled source
        #pragma unroll
        for (int i = 0; i < 8; ++i) {
            const int t = i >> 1;                    // compile-time tile id
            const int c = (i & 1) * 4 + wave;        // chunk 0..7 in tile
            const int r = c * 16 + (lane >> 2);      // row in 128-row tile
            const int slot = lane & 3;
            const int kcg = slot ^ ((r >> 1) & 3);   // global k-chunk for this slot
            const unsigned short* gp; int rb;
            if (t == 0)      { gp = Ah; rb = row0; }
            else if (t == 1) { gp = Al; rb = row0; }
            else if (t == 2) { gp = Wh; rb = col0; }
            else             { gp = Wl; rb = col0; }
            const unsigned short* ga = gp + (size_t)(rb + r) * K + k0 + kcg * 8;
            gload_lds16(ga, &sm[t * 4096 + c * 512]);
        }
        __syncthreads();

        // ---- fragments (swizzled ds_read_b128)
        short8 fa_h[4], fa_l[4], fw_h[4], fw_l[4];
        #pragma unroll
        for (int m = 0; m < 4; ++m) {
            int ra = wr * 64 + m * 16 + rsel;
            int offa = ra * 32 + ((kc ^ ((ra >> 1) & 3)) * 8);
            fa_h[m] = *(const short8*)&sm[offa];
            fa_l[m] = *(const short8*)&sm[4096 + offa];
            int rw = wc * 64 + m * 16 + rsel;
            int offw = rw * 32 + ((kc ^ ((rw >> 1) & 3)) * 8);
            fw_h[m] = *(const short8*)&sm[8192 + offw];
            fw_l[m] = *(const short8*)&sm[12288 + offw];
        }

        // ---- 48 MFMA: hi*hi + lo*hi + hi*lo
        #pragma unroll
        for (int m = 0; m < 4; ++m)
            #pragma unroll
            for (int n = 0; n < 4; ++n) {
                acc[m][n] = __builtin_amdgcn_mfma_f32_16x16x32_bf16(fa_h[m], fw_h[n], acc[m][n], 0, 0, 0);
                acc[m][n] = __builtin_amdgcn_mfma_f32_16x16x32_bf16(fa_l[m], fw_h[n], acc[m][n], 0, 0, 0);
                acc[m][n] = __builtin_amdgcn_mfma_f32_16x16x32_bf16(fa_h[m], fw_l[n], acc[m][n], 0, 0, 0);
            }
        __syncthreads();
    }

    // ---- epilogue: D layout col=lane&15, row=(lane>>4)*4+j
    const int jrow = lane >> 4;
    #pragma unroll
    for (int n = 0; n < 4; ++n) {
        int c = col0 + wc * 64 + n * 16 + rsel;
        float bv = bias[c];
        #pragma unroll
        for (int m = 0; m < 4; ++m) {
            #pragma unroll
            for (int j = 0; j < 4; ++j) {
                int r = row0 + wr * 64 + m * 16 + jrow * 4 + j;
                float v = acc[m][n][j] + bv;
                if (EPI == 0) {
                    outf[(size_t)r * N + c] = v;
                } else if (EPI == 1) {
                    float gg = gelu_f(v);
                    unsigned short h, l;
                    split_bf16(gg, h, l);
                    outh[(size_t)r * N + c] = h;
                    outl[(size_t)r * N + c] = l;
                } else if (EPI == 2) {
                    int orow = win_to_xrow(r, shifted);
                    outf[(size_t)orow * CC + c] += v;
                } else {
                    outf[(size_t)r * CC + c] += v;
                }
            }
        }
    }
}

// ---------------- windowed attention (fp32 math, bf16 hi/lo out) -------------
__global__ __launch_bounds__(64) void attn_kernel(const float* __restrict__ qkv,
    unsigned short* __restrict__ oh, unsigned short* __restrict__ ol,
    const float* __restrict__ rpb, int shifted)
{
    int bh = blockIdx.x;
    int bn = bh >> 5, h = bh & 31;
    __shared__ float qs[49][32], ks[49][32], vs[49][32];
    __shared__ float ss[49][50];
    int lane = threadIdx.x;
    for (int idx = lane; idx < 49 * 32; idx += 64) {
        int t = idx >> 5, d = idx & 31;
        const float* p = qkv + (size_t)(bn * 49 + t) * 3072 + h * 32 + d;
        qs[t][d] = p[0];
        ks[t][d] = p[1024];
        vs[t][d] = p[2048];
    }
    __syncthreads();
    if (lane < 49) {
        int i = lane;
        int ih = i / 7, iw = i - ih * 7;
        int w = bn & 3, wh = w >> 1, ww_ = w & 1;
        int gh = wh * 7 + ih, gw = ww_ * 7 + iw;
        int li = (gh < 7 ? 0 : (gh < 11 ? 1 : 2)) * 3 + (gw < 7 ? 0 : (gw < 11 ? 1 : 2));
        float qreg[32];
        #pragma unroll
        for (int d = 0; d < 32; ++d) qreg[d] = qs[i][d] * SCALE;
        float mx = -1e30f;
        for (int j = 0; j < 49; ++j) {
            int jh = j / 7, jw = j - jh * 7;
            float dot = 0.f;
            #pragma unroll
            for (int d = 0; d < 32; ++d) dot = fmaf(qreg[d], ks[j][d], dot);
            int ridx = (ih - jh + 6) * 13 + (iw - jw + 6);
            float val = dot + rpb[ridx * 32 + h];
            if (shifted) {
                int gjh = wh * 7 + jh, gjw = ww_ * 7 + jw;
                int lj = (gjh < 7 ? 0 : (gjh < 11 ? 1 : 2)) * 3 +
                         (gjw < 7 ? 0 : (gjw < 11 ? 1 : 2));
                if (li != lj) val -= 100.0f;
            }
            ss[i][j] = val;
            mx = fmaxf(mx, val);
        }
        float denom = 0.f;
        for (int j = 0; j < 49; ++j) {
            float e = expf(ss[i][j] - mx);
            ss[i][j] = e;
            denom += e;
        }
        float rd = 1.0f / denom;
        size_t obase = (size_t)(bn * 49 + i) * CC + h * 32;
        #pragma unroll 4
        for (int d = 0; d < 32; ++d) {
            float acc = 0.f;
            for (int j = 0; j < 49; ++j) acc = fmaf(ss[i][j], vs[j][d], acc);
            float vout = acc * rd;
            unsigned short hb, lb;
            split_bf16(vout, hb, lb);
            oh[obase + d] = hb;
            ol[obase + d] = lb;
        }
    }
}

// ---------------- global-avg-pool + LayerNorm --------------------------------
__global__ __launch_bounds__(256) void pool_ln_kernel(const float* __restrict__ X,
    const float* __restrict__ g, const float* __restrict__ bta, float* __restrict__ out)
{
    int b = blockIdx.x, tid = threadIdx.x;
    int lane = tid & 63, wid = tid >> 6;
    const float* base = X + (size_t)b * 196 * CC + tid * 4;
    float a0 = 0, a1 = 0, a2 = 0, a3 = 0;
    for (int t = 0; t < 196; ++t) {
        float4 v = *(const float4*)(base + (size_t)t * CC);
        a0 += v.x; a1 += v.y; a2 += v.z; a3 += v.w;
    }
    const float inv196 = 1.0f / 196.0f;
    float p0 = a0 * inv196, p1 = a1 * inv196, p2 = a2 * inv196, p3 = a3 * inv196;
    float s = p0 + p1 + p2 + p3;
    #pragma unroll
    for (int o = 32; o; o >>= 1) s += __shfl_xor(s, o);
    __shared__ float sred[4], ssred[4];
    if (lane == 0) sred[wid] = s;
    __syncthreads();
    float mean = (sred[0] + sred[1] + sred[2] + sred[3]) * (1.0f / CC);
    float d0 = p0 - mean, d1 = p1 - mean, d2 = p2 - mean, d3 = p3 - mean;
    float ss = d0 * d0 + d1 * d1 + d2 * d2 + d3 * d3;
    #pragma unroll
    for (int o = 32; o; o >>= 1) ss += __shfl_xor(ss, o);
    if (lane == 0) ssred[wid] = ss;
    __syncthreads();
    float var = (ssred[0] + ssred[1] + ssred[2] + ssred[3]) * (1.0f / CC);
    float inv = 1.0f / sqrtf(var + 1e-5f);
    float4 gv = *(const float4*)(g + tid * 4);
    float4 bv = *(const float4*)(bta + tid * 4);
    float4 o4;
    o4.x = d0 * inv * gv.x + bv.x;
    o4.y = d1 * inv * gv.y + bv.y;
    o4.z = d2 * inv * gv.z + bv.z;
    o4.w = d3 * inv * gv.w + bv.w;
    *(float4*)(out + (size_t)b * CC + tid * 4) = o4;
}

// ---------------- tiny head GEMM ---------------------------------------------
__global__ void head_gemm_kernel(const float* __restrict__ A, const float* __restrict__ W,
    const float* __restrict__ bias, float* __restrict__ out, int M, int K, int N, int act)
{
    int idx = blockIdx.x * blockDim.x + threadIdx.x;
    if (idx >= M * N) return;
    int r = idx / N, c = idx - r * N;
    float s = bias[c];
    for (int k = 0; k < K; ++k) s = fmaf(A[(size_t)r * K + k], W[(size_t)k * N + c], s);
    if (act) s = gelu_f(s);
    out[idx] = s;
}

// ---------------- launch ------------------------------------------------------
extern "C" void kernel_launch(void* const* d_in, const int* in_sizes, int n_in,
                              void* d_out, int out_size, void* d_ws, size_t ws_size,
                              hipStream_t stream) {
    const float* x = (const float*)d_in[0];
    auto P = [&](int i) { return (const float*)d_in[i]; };

    float *X, *QKV, *H0, *H1, *H2;
    unsigned short *Bh, *Bl, *Ch, *Cl;
    unsigned short *Wqh, *Wql, *Wph, *Wpl, *W1h, *W1l, *W2h, *W2l;
    { void* p;
      hipGetSymbolAddress(&p, HIP_SYMBOL(g_X));   X   = (float*)p;
      hipGetSymbolAddress(&p, HIP_SYMBOL(g_QKV)); QKV = (float*)p;
      hipGetSymbolAddress(&p, HIP_SYMBOL(g_Bh));  Bh  = (unsigned short*)p;
      hipGetSymbolAddress(&p, HIP_SYMBOL(g_Bl));  Bl  = (unsigned short*)p;
      hipGetSymbolAddress(&p, HIP_SYMBOL(g_Ch));  Ch  = (unsigned short*)p;
      hipGetSymbolAddress(&p, HIP_SYMBOL(g_Cl));  Cl  = (unsigned short*)p;
      hipGetSymbolAddress(&p, HIP_SYMBOL(g_Wqkv_h)); Wqh = (unsigned short*)p;
      hipGetSymbolAddress(&p, HIP_SYMBOL(g_Wqkv_l)); Wql = (unsigned short*)p;
      hipGetSymbolAddress(&p, HIP_SYMBOL(g_Wproj_h)); Wph = (unsigned short*)p;
      hipGetSymbolAddress(&p, HIP_SYMBOL(g_Wproj_l)); Wpl = (unsigned short*)p;
      hipGetSymbolAddress(&p, HIP_SYMBOL(g_Wfc1_h)); W1h = (unsigned short*)p;
      hipGetSymbolAddress(&p, HIP_SYMBOL(g_Wfc1_l)); W1l = (unsigned short*)p;
      hipGetSymbolAddress(&p, HIP_SYMBOL(g_Wfc2_h)); W2h = (unsigned short*)p;
      hipGetSymbolAddress(&p, HIP_SYMBOL(g_Wfc2_l)); W2l = (unsigned short*)p;
      hipGetSymbolAddress(&p, HIP_SYMBOL(g_H0));  H0 = (float*)p;
      hipGetSymbolAddress(&p, HIP_SYMBOL(g_H1));  H1 = (float*)p;
      hipGetSymbolAddress(&p, HIP_SYMBOL(g_H2));  H2 = (float*)p;
    }

    hipMemcpyAsync(X, x, (size_t)NTOK * CC * sizeof(float),
                   hipMemcpyDeviceToDevice, stream);

    // weight conversion + transpose (per launch; weights are inputs)
    for (int blk = 0; blk < 2; ++blk) {
        int base = 1 + blk * 13;
        convw_kernel<<<dim3(3072/32, 1024/32), 256, 0, stream>>>(
            P(base + 2), Wqh + (size_t)blk*3072*1024, Wql + (size_t)blk*3072*1024, 1024, 3072);
        convw_kernel<<<dim3(1024/32, 1024/32), 256, 0, stream>>>(
            P(base + 5), Wph + (size_t)blk*1024*1024, Wpl + (size_t)blk*1024*1024, 1024, 1024);
        convw_kernel<<<dim3(4096/32, 1024/32), 256, 0, stream>>>(
            P(base + 9), W1h + (size_t)blk*4096*1024, W1l + (size_t)blk*4096*1024, 1024, 4096);
        convw_kernel<<<dim3(1024/32, 4096/32), 256, 0, stream>>>(
            P(base + 11), W2h + (size_t)blk*1024*4096, W2l + (size_t)blk*1024*4096, 4096, 1024);
    }

    for (int blk = 0; blk < 2; ++blk) {
        int base = 1 + blk * 13;
        const float *ln1g = P(base + 0), *ln1b = P(base + 1);
        const float *qkvb = P(base + 3);
        const float *rpb  = P(base + 4);
        const float *projb = P(base + 6);
        const float *ln2g = P(base + 7), *ln2b = P(base + 8);
        const float *fc1b = P(base + 10);
        const float *fc2b = P(base + 12);
        int shifted = blk;
        const unsigned short* wq_h = Wqh + (size_t)blk*3072*1024;
        const unsigned short* wq_l = Wql + (size_t)blk*3072*1024;
        const unsigned short* wp_h = Wph + (size_t)blk*1024*1024;
        const unsigned short* wp_l = Wpl + (size_t)blk*1024*1024;
        const unsigned short* w1_h = W1h + (size_t)blk*4096*1024;
        const unsigned short* w1_l = W1l + (size_t)blk*4096*1024;
        const unsigned short* w2_h = W2h + (size_t)blk*1024*4096;
        const unsigned short* w2_l = W2l + (size_t)blk*1024*4096;

        // LN1 + window partition (+shift): X -> Bh/Bl (window order)
        ln_kernel<<<NTOK / 4, 256, 0, stream>>>(X, ln1g, ln1b, Bh, Bl, shifted, 1);
        // QKV: [12544,1024] x [3072,1024]^T -> QKV fp32
        gemm_mfma<0><<<dim3(3072/128, NTOK/128), 256, 0, stream>>>(
            Bh, Bl, wq_h, wq_l, qkvb, QKV, nullptr, nullptr, 3072, 1024, 0);
        // attention -> Bh/Bl (window order)
        attn_kernel<<<256 * NH, 64, 0, stream>>>(QKV, Bh, Bl, rpb, shifted);
        // proj + window-reverse (+unshift) + residual into X
        gemm_mfma<2><<<dim3(1024/128, NTOK/128), 256, 0, stream>>>(
            Bh, Bl, wp_h, wp_l, projb, X, nullptr, nullptr, 1024, 1024, shifted);
        // LN2: X -> Bh/Bl
        ln_kernel<<<NTOK / 4, 256, 0, stream>>>(X, ln2g, ln2b, Bh, Bl, 0, 0);
        // FC1 + gelu -> Ch/Cl
        gemm_mfma<1><<<dim3(4096/128, NTOK/128), 256, 0, stream>>>(
            Bh, Bl, w1_h, w1_l, fc1b, nullptr, Ch, Cl, 4096, 1024, 0);
        // FC2 + residual into X
        gemm_mfma<3><<<dim3(1024/128, NTOK/128), 256, 0, stream>>>(
            Ch, Cl, w2_h, w2_l, fc2b, X, nullptr, nullptr, 1024, 4096, 0);
    }

    // head
    pool_ln_kernel<<<64, 256, 0, stream>>>(X, P(27), P(28), H0);
    head_gemm_kernel<<<(64 * 512 + 255) / 256, 256, 0, stream>>>(
        H0, P(29), P(30), H1, 64, 1024, 512, 1);
    head_gemm_kernel<<<(64 * 128 + 255) / 256, 256, 0, stream>>>(
        H1, P(31), P(32), H2, 64, 512, 128, 1);
    head_gemm_kernel<<<1, 128, 0, stream>>>(
        H2, P(33), P(34), (float*)d_out, 64, 128, 2, 0);
}

// Round 4
// 3068.240 us; speedup vs baseline: 3.1309x; 1.3659x over previous
//
#include <hip/hip_runtime.h>
#include <hip/hip_bf16.h>
#include <math.h>

// ---------------- problem constants ----------------
#define BB 64
#define CC 1024
#define NH 32
#define NTOK (BB * 14 * 14)      // 12544
#define SCALE 0.17677669529663687f  // 32^-0.5

typedef __attribute__((ext_vector_type(8))) short short8;
typedef __attribute__((ext_vector_type(4))) float f32x4;

// ---------------- static device workspace ----------------
__device__ __align__(16) float  g_X  [(size_t)NTOK * CC];        // residual (fp32)
__device__ __align__(16) float  g_QKV[(size_t)NTOK * 3072];      // qkv out (fp32)
__device__ __align__(16) unsigned short g_Bh[(size_t)NTOK * CC];  // 1024-wide act hi
__device__ __align__(16) unsigned short g_Bl[(size_t)NTOK * CC];  // 1024-wide act lo
__device__ __align__(16) unsigned short g_Ch[(size_t)NTOK * 4096];// fc1 out hi
__device__ __align__(16) unsigned short g_Cl[(size_t)NTOK * 4096];// fc1 out lo
// transposed bf16 weights [N][K], hi/lo, 2 blocks
__device__ __align__(16) unsigned short g_Wqkv_h[(size_t)2*3072*1024], g_Wqkv_l[(size_t)2*3072*1024];
__device__ __align__(16) unsigned short g_Wproj_h[(size_t)2*1024*1024], g_Wproj_l[(size_t)2*1024*1024];
__device__ __align__(16) unsigned short g_Wfc1_h[(size_t)2*4096*1024], g_Wfc1_l[(size_t)2*4096*1024];
__device__ __align__(16) unsigned short g_Wfc2_h[(size_t)2*1024*4096], g_Wfc2_l[(size_t)2*1024*4096];
__device__ __align__(16) float g_H0[64 * CC];
__device__ __align__(16) float g_H1[64 * 512];
__device__ __align__(16) float g_H2[64 * 128];

__device__ __forceinline__ float gelu_f(float x) {
    return 0.5f * x * (1.0f + erff(x * 0.70710678118654752f));
}

__device__ __forceinline__ void split_bf16(float v, unsigned short& h, unsigned short& l) {
    __hip_bfloat16 hb = __float2bfloat16(v);
    float hf = __bfloat162float(hb);
    __hip_bfloat16 lb = __float2bfloat16(v - hf);
    h = *(unsigned short*)&hb;
    l = *(unsigned short*)&lb;
}

// window-order row r (bn*49+t) -> row in X ([B,14,14] flattened)
__device__ __forceinline__ int win_to_xrow(int r, int shifted) {
    int bn = r / 49, t = r - bn * 49;
    int b = bn >> 2, w = bn & 3;
    int wh = w >> 1, ww_ = w & 1;
    int th = t / 7, tw = t - th * 7;
    int gh = wh * 7 + th, gw = ww_ * 7 + tw;
    if (shifted) { gh = gh + 3; if (gh >= 14) gh -= 14; gw = gw + 3; if (gw >= 14) gw -= 14; }
    return b * 196 + gh * 14 + gw;
}

__device__ __forceinline__ void gload_lds16(const void* g, void* l) {
    __builtin_amdgcn_global_load_lds(
        (const __attribute__((address_space(1))) unsigned int*)g,
        (__attribute__((address_space(3))) unsigned int*)l, 16, 0, 0);
}

// ---------------- weight convert + transpose: W[K][N] fp32 -> WT[N][K] bf16 hi/lo
__global__ __launch_bounds__(256) void convw_kernel(const float* __restrict__ W,
    unsigned short* __restrict__ Wh, unsigned short* __restrict__ Wl, int K, int N)
{
    __shared__ float t[32][33];
    int n0 = blockIdx.x * 32, k0 = blockIdx.y * 32;
    int tx = threadIdx.x & 31, ty = threadIdx.x >> 5;
    #pragma unroll
    for (int i = 0; i < 4; ++i)
        t[ty + 8 * i][tx] = W[(size_t)(k0 + ty + 8 * i) * N + n0 + tx];
    __syncthreads();
    #pragma unroll
    for (int i = 0; i < 4; ++i) {
        int n = ty + 8 * i;
        float v = t[tx][n];                 // W[k0+tx][n0+n]
        unsigned short h, l;
        split_bf16(v, h, l);
        size_t o = (size_t)(n0 + n) * K + k0 + tx;
        Wh[o] = h; Wl[o] = l;
    }
}

// ---------------- LayerNorm -> bf16 hi/lo (optional window partition+shift) ---
__global__ __launch_bounds__(256) void ln_kernel(const float* __restrict__ X,
    const float* __restrict__ g, const float* __restrict__ bta,
    unsigned short* __restrict__ outh, unsigned short* __restrict__ outl,
    int shifted, int partition)
{
    int token = blockIdx.x * 4 + (threadIdx.x >> 6);
    int lane = threadIdx.x & 63;
    int xrow = partition ? win_to_xrow(token, shifted) : token;
    const float4* src = (const float4*)(X + (size_t)xrow * CC);
    float4 v[4];
    float s = 0.f;
    #pragma unroll
    for (int w = 0; w < 4; ++w) {
        v[w] = src[w * 64 + lane];
        s += v[w].x + v[w].y + v[w].z + v[w].w;
    }
    #pragma unroll
    for (int o = 32; o; o >>= 1) s += __shfl_xor(s, o);
    float mean = s * (1.0f / CC);
    float ss = 0.f;
    #pragma unroll
    for (int w = 0; w < 4; ++w) {
        float d0 = v[w].x - mean, d1 = v[w].y - mean, d2 = v[w].z - mean, d3 = v[w].w - mean;
        ss += d0 * d0 + d1 * d1 + d2 * d2 + d3 * d3;
    }
    #pragma unroll
    for (int o = 32; o; o >>= 1) ss += __shfl_xor(ss, o);
    float inv = 1.0f / sqrtf(ss * (1.0f / CC) + 1e-5f);
    #pragma unroll
    for (int w = 0; w < 4; ++w) {
        int c4 = w * 64 + lane;
        float4 gv = *(const float4*)(g + c4 * 4);
        float4 bv = *(const float4*)(bta + c4 * 4);
        float o0 = (v[w].x - mean) * inv * gv.x + bv.x;
        float o1 = (v[w].y - mean) * inv * gv.y + bv.y;
        float o2 = (v[w].z - mean) * inv * gv.z + bv.z;
        float o3 = (v[w].w - mean) * inv * gv.w + bv.w;
        ushort4 uh, ul;
        split_bf16(o0, uh.x, ul.x); split_bf16(o1, uh.y, ul.y);
        split_bf16(o2, uh.z, ul.z); split_bf16(o3, uh.w, ul.w);
        *(ushort4*)(outh + (size_t)token * CC + c4 * 4) = uh;
        *(ushort4*)(outl + (size_t)token * CC + c4 * 4) = ul;
    }
}

// ---------------- bf16x3 MFMA GEMM: C = A[M][K] * WT[N][K]^T --------------
// 128x128 tile, BK=64, 4 waves (2x2), 4x4 16x16x32 frags per wave,
// 96 MFMA per wave per K-tile. 4 LDS tiles [128][64]bf16 (Ah,Al,Wh,Wl), 64KB,
// single-buffered, full 8-slot XOR swizzle (slot ^= row&7) on both sides.
// EPI: 0 fp32 store+bias (QKV); 1 gelu -> bf16 hi/lo store (FC1);
//      2 residual += into X via window map (proj); 3 residual += direct (FC2)
template<int EPI>
__global__ __launch_bounds__(256, 2) void gemm_mfma(
    const unsigned short* __restrict__ Ah, const unsigned short* __restrict__ Al,
    const unsigned short* __restrict__ Wh, const unsigned short* __restrict__ Wl,
    const float* __restrict__ bias,
    float* __restrict__ outf, unsigned short* __restrict__ outh,
    unsigned short* __restrict__ outl, int N, int K, int shifted)
{
    __shared__ unsigned short sm[32768];   // 4 tiles x [128][64] bf16, 16KB each
    const int tid = threadIdx.x;
    const int wave = tid >> 6, lane = tid & 63;
    const int wr = wave >> 1, wc = wave & 1;
    const int row0 = blockIdx.y * 128, col0 = blockIdx.x * 128;
    const int rsel = lane & 15;

    f32x4 acc[4][4] = {};

    // staging coords (constant per thread): 4 sub-issues per tile
    const int srow_base = tid >> 3;          // + sub*32
    const int sslot = tid & 7;

    for (int k0 = 0; k0 < K; k0 += 64) {
        // ---- stage 4 tiles via global_load_lds (linear dest, swizzled source)
        #pragma unroll
        for (int i = 0; i < 16; ++i) {
            const int t = i >> 2;               // tile id 0..3 (compile-time)
            const int sub = i & 3;              // 32-row group within tile
            const int row = sub * 32 + srow_base;
            const int c = sslot ^ (row & 7);    // global k-chunk for this slot
            const unsigned short* gp; int rb;
            if (t == 0)      { gp = Ah; rb = row0; }
            else if (t == 1) { gp = Al; rb = row0; }
            else if (t == 2) { gp = Wh; rb = col0; }
            else             { gp = Wl; rb = col0; }
            const unsigned short* ga = gp + (size_t)(rb + row) * K + k0 + c * 8;
            gload_lds16(ga, &sm[t * 8192 + sub * 2048 + tid * 8]);
        }
        __syncthreads();

        // ---- per 32-K step: read frags (swizzled) + 48 MFMA
        #pragma unroll
        for (int kk = 0; kk < 2; ++kk) {
            const int kc8 = kk * 4 + (lane >> 4);   // k-chunk 0..7 within BK=64
            short8 fa_h[4], fw_h[4], fa_l[4], fw_l[4];
            #pragma unroll
            for (int m = 0; m < 4; ++m) {
                int ra = wr * 64 + m * 16 + rsel;
                int oa = ra * 64 + ((kc8 ^ (ra & 7)) * 8);
                fa_h[m] = *(const short8*)&sm[oa];
                int rw = wc * 64 + m * 16 + rsel;
                int ow = rw * 64 + ((kc8 ^ (rw & 7)) * 8);
                fw_h[m] = *(const short8*)&sm[16384 + ow];
            }
            #pragma unroll
            for (int m = 0; m < 4; ++m)
                #pragma unroll
                for (int n = 0; n < 4; ++n)
                    acc[m][n] = __builtin_amdgcn_mfma_f32_16x16x32_bf16(fa_h[m], fw_h[n], acc[m][n], 0, 0, 0);
            #pragma unroll
            for (int m = 0; m < 4; ++m) {
                int ra = wr * 64 + m * 16 + rsel;
                int oa = ra * 64 + ((kc8 ^ (ra & 7)) * 8);
                fa_l[m] = *(const short8*)&sm[8192 + oa];
            }
            #pragma unroll
            for (int m = 0; m < 4; ++m)
                #pragma unroll
                for (int n = 0; n < 4; ++n)
                    acc[m][n] = __builtin_amdgcn_mfma_f32_16x16x32_bf16(fa_l[m], fw_h[n], acc[m][n], 0, 0, 0);
            #pragma unroll
            for (int n = 0; n < 4; ++n) {
                int rw = wc * 64 + n * 16 + rsel;
                int ow = rw * 64 + ((kc8 ^ (rw & 7)) * 8);
                fw_l[n] = *(const short8*)&sm[24576 + ow];
            }
            #pragma unroll
            for (int m = 0; m < 4; ++m)
                #pragma unroll
                for (int n = 0; n < 4; ++n)
                    acc[m][n] = __builtin_amdgcn_mfma_f32_16x16x32_bf16(fa_h[m], fw_l[n], acc[m][n], 0, 0, 0);
        }
        __syncthreads();
    }

    // ---- epilogue: D layout col=lane&15, row=(lane>>4)*4+j
    const int jrow = lane >> 4;
    #pragma unroll
    for (int n = 0; n < 4; ++n) {
        int c = col0 + wc * 64 + n * 16 + rsel;
        float bv = bias[c];
        #pragma unroll
        for (int m = 0; m < 4; ++m) {
            #pragma unroll
            for (int j = 0; j < 4; ++j) {
                int r = row0 + wr * 64 + m * 16 + jrow * 4 + j;
                float v = acc[m][n][j] + bv;
                if (EPI == 0) {
                    outf[(size_t)r * N + c] = v;
                } else if (EPI == 1) {
                    float gg = gelu_f(v);
                    unsigned short h, l;
                    split_bf16(gg, h, l);
                    outh[(size_t)r * N + c] = h;
                    outl[(size_t)r * N + c] = l;
                } else if (EPI == 2) {
                    int orow = win_to_xrow(r, shifted);
                    outf[(size_t)orow * CC + c] += v;
                } else {
                    outf[(size_t)r * CC + c] += v;
                }
            }
        }
    }
}

// ---------------- windowed attention (fp32 math, bf16 hi/lo out) -------------
__global__ __launch_bounds__(64) void attn_kernel(const float* __restrict__ qkv,
    unsigned short* __restrict__ oh, unsigned short* __restrict__ ol,
    const float* __restrict__ rpb, int shifted)
{
    int bh = blockIdx.x;
    int bn = bh >> 5, h = bh & 31;
    __shared__ float qs[49][32], ks[49][32], vs[49][32];
    __shared__ float ss[49][50];
    int lane = threadIdx.x;
    for (int idx = lane; idx < 49 * 32; idx += 64) {
        int t = idx >> 5, d = idx & 31;
        const float* p = qkv + (size_t)(bn * 49 + t) * 3072 + h * 32 + d;
        qs[t][d] = p[0];
        ks[t][d] = p[1024];
        vs[t][d] = p[2048];
    }
    __syncthreads();
    if (lane < 49) {
        int i = lane;
        int ih = i / 7, iw = i - ih * 7;
        int w = bn & 3, wh = w >> 1, ww_ = w & 1;
        int gh = wh * 7 + ih, gw = ww_ * 7 + iw;
        int li = (gh < 7 ? 0 : (gh < 11 ? 1 : 2)) * 3 + (gw < 7 ? 0 : (gw < 11 ? 1 : 2));
        float qreg[32];
        #pragma unroll
        for (int d = 0; d < 32; ++d) qreg[d] = qs[i][d] * SCALE;
        float mx = -1e30f;
        for (int j = 0; j < 49; ++j) {
            int jh = j / 7, jw = j - jh * 7;
            float dot = 0.f;
            #pragma unroll
            for (int d = 0; d < 32; ++d) dot = fmaf(qreg[d], ks[j][d], dot);
            int ridx = (ih - jh + 6) * 13 + (iw - jw + 6);
            float val = dot + rpb[ridx * 32 + h];
            if (shifted) {
                int gjh = wh * 7 + jh, gjw = ww_ * 7 + jw;
                int lj = (gjh < 7 ? 0 : (gjh < 11 ? 1 : 2)) * 3 +
                         (gjw < 7 ? 0 : (gjw < 11 ? 1 : 2));
                if (li != lj) val -= 100.0f;
            }
            ss[i][j] = val;
            mx = fmaxf(mx, val);
        }
        float denom = 0.f;
        for (int j = 0; j < 49; ++j) {
            float e = expf(ss[i][j] - mx);
            ss[i][j] = e;
            denom += e;
        }
        float rd = 1.0f / denom;
        size_t obase = (size_t)(bn * 49 + i) * CC + h * 32;
        #pragma unroll 4
        for (int d = 0; d < 32; ++d) {
            float acc = 0.f;
            for (int j = 0; j < 49; ++j) acc = fmaf(ss[i][j], vs[j][d], acc);
            float vout = acc * rd;
            unsigned short hb, lb;
            split_bf16(vout, hb, lb);
            oh[obase + d] = hb;
            ol[obase + d] = lb;
        }
    }
}

// ---------------- global-avg-pool + LayerNorm --------------------------------
__global__ __launch_bounds__(256) void pool_ln_kernel(const float* __restrict__ X,
    const float* __restrict__ g, const float* __restrict__ bta, float* __restrict__ out)
{
    int b = blockIdx.x, tid = threadIdx.x;
    int lane = tid & 63, wid = tid >> 6;
    const float* base = X + (size_t)b * 196 * CC + tid * 4;
    float a0 = 0, a1 = 0, a2 = 0, a3 = 0;
    for (int t = 0; t < 196; ++t) {
        float4 v = *(const float4*)(base + (size_t)t * CC);
        a0 += v.x; a1 += v.y; a2 += v.z; a3 += v.w;
    }
    const float inv196 = 1.0f / 196.0f;
    float p0 = a0 * inv196, p1 = a1 * inv196, p2 = a2 * inv196, p3 = a3 * inv196;
    float s = p0 + p1 + p2 + p3;
    #pragma unroll
    for (int o = 32; o; o >>= 1) s += __shfl_xor(s, o);
    __shared__ float sred[4], ssred[4];
    if (lane == 0) sred[wid] = s;
    __syncthreads();
    float mean = (sred[0] + sred[1] + sred[2] + sred[3]) * (1.0f / CC);
    float d0 = p0 - mean, d1 = p1 - mean, d2 = p2 - mean, d3 = p3 - mean;
    float ss = d0 * d0 + d1 * d1 + d2 * d2 + d3 * d3;
    #pragma unroll
    for (int o = 32; o; o >>= 1) ss += __shfl_xor(ss, o);
    if (lane == 0) ssred[wid] = ss;
    __syncthreads();
    float var = (ssred[0] + ssred[1] + ssred[2] + ssred[3]) * (1.0f / CC);
    float inv = 1.0f / sqrtf(var + 1e-5f);
    float4 gv = *(const float4*)(g + tid * 4);
    float4 bv = *(const float4*)(bta + tid * 4);
    float4 o4;
    o4.x = d0 * inv * gv.x + bv.x;
    o4.y = d1 * inv * gv.y + bv.y;
    o4.z = d2 * inv * gv.z + bv.z;
    o4.w = d3 * inv * gv.w + bv.w;
    *(float4*)(out + (size_t)b * CC + tid * 4) = o4;
}

// ---------------- tiny head GEMM ---------------------------------------------
__global__ void head_gemm_kernel(const float* __restrict__ A, const float* __restrict__ W,
    const float* __restrict__ bias, float* __restrict__ out, int M, int K, int N, int act)
{
    int idx = blockIdx.x * blockDim.x + threadIdx.x;
    if (idx >= M * N) return;
    int r = idx / N, c = idx - r * N;
    float s = bias[c];
    for (int k = 0; k < K; ++k) s = fmaf(A[(size_t)r * K + k], W[(size_t)k * N + c], s);
    if (act) s = gelu_f(s);
    out[idx] = s;
}

// ---------------- launch ------------------------------------------------------
extern "C" void kernel_launch(void* const* d_in, const int* in_sizes, int n_in,
                              void* d_out, int out_size, void* d_ws, size_t ws_size,
                              hipStream_t stream) {
    const float* x = (const float*)d_in[0];
    auto P = [&](int i) { return (const float*)d_in[i]; };

    float *X, *QKV, *H0, *H1, *H2;
    unsigned short *Bh, *Bl, *Ch, *Cl;
    unsigned short *Wqh, *Wql, *Wph, *Wpl, *W1h, *W1l, *W2h, *W2l;
    { void* p;
      hipGetSymbolAddress(&p, HIP_SYMBOL(g_X));   X   = (float*)p;
      hipGetSymbolAddress(&p, HIP_SYMBOL(g_QKV)); QKV = (float*)p;
      hipGetSymbolAddress(&p, HIP_SYMBOL(g_Bh));  Bh  = (unsigned short*)p;
      hipGetSymbolAddress(&p, HIP_SYMBOL(g_Bl));  Bl  = (unsigned short*)p;
      hipGetSymbolAddress(&p, HIP_SYMBOL(g_Ch));  Ch  = (unsigned short*)p;
      hipGetSymbolAddress(&p, HIP_SYMBOL(g_Cl));  Cl  = (unsigned short*)p;
      hipGetSymbolAddress(&p, HIP_SYMBOL(g_Wqkv_h)); Wqh = (unsigned short*)p;
      hipGetSymbolAddress(&p, HIP_SYMBOL(g_Wqkv_l)); Wql = (unsigned short*)p;
      hipGetSymbolAddress(&p, HIP_SYMBOL(g_Wproj_h)); Wph = (unsigned short*)p;
      hipGetSymbolAddress(&p, HIP_SYMBOL(g_Wproj_l)); Wpl = (unsigned short*)p;
      hipGetSymbolAddress(&p, HIP_SYMBOL(g_Wfc1_h)); W1h = (unsigned short*)p;
      hipGetSymbolAddress(&p, HIP_SYMBOL(g_Wfc1_l)); W1l = (unsigned short*)p;
      hipGetSymbolAddress(&p, HIP_SYMBOL(g_Wfc2_h)); W2h = (unsigned short*)p;
      hipGetSymbolAddress(&p, HIP_SYMBOL(g_Wfc2_l)); W2l = (unsigned short*)p;
      hipGetSymbolAddress(&p, HIP_SYMBOL(g_H0));  H0 = (float*)p;
      hipGetSymbolAddress(&p, HIP_SYMBOL(g_H1));  H1 = (float*)p;
      hipGetSymbolAddress(&p, HIP_SYMBOL(g_H2));  H2 = (float*)p;
    }

    hipMemcpyAsync(X, x, (size_t)NTOK * CC * sizeof(float),
                   hipMemcpyDeviceToDevice, stream);

    // weight conversion + transpose (per launch; weights are inputs)
    for (int blk = 0; blk < 2; ++blk) {
        int base = 1 + blk * 13;
        convw_kernel<<<dim3(3072/32, 1024/32), 256, 0, stream>>>(
            P(base + 2), Wqh + (size_t)blk*3072*1024, Wql + (size_t)blk*3072*1024, 1024, 3072);
        convw_kernel<<<dim3(1024/32, 1024/32), 256, 0, stream>>>(
            P(base + 5), Wph + (size_t)blk*1024*1024, Wpl + (size_t)blk*1024*1024, 1024, 1024);
        convw_kernel<<<dim3(4096/32, 1024/32), 256, 0, stream>>>(
            P(base + 9), W1h + (size_t)blk*4096*1024, W1l + (size_t)blk*4096*1024, 1024, 4096);
        convw_kernel<<<dim3(1024/32, 4096/32), 256, 0, stream>>>(
            P(base + 11), W2h + (size_t)blk*1024*4096, W2l + (size_t)blk*1024*4096, 4096, 1024);
    }

    for (int blk = 0; blk < 2; ++blk) {
        int base = 1 + blk * 13;
        const float *ln1g = P(base + 0), *ln1b = P(base + 1);
        const float *qkvb = P(base + 3);
        const float *rpb  = P(base + 4);
        const float *projb = P(base + 6);
        const float *ln2g = P(base + 7), *ln2b = P(base + 8);
        const float *fc1b = P(base + 10);
        const float *fc2b = P(base + 12);
        int shifted = blk;
        const unsigned short* wq_h = Wqh + (size_t)blk*3072*1024;
        const unsigned short* wq_l = Wql + (size_t)blk*3072*1024;
        const unsigned short* wp_h = Wph + (size_t)blk*1024*1024;
        const unsigned short* wp_l = Wpl + (size_t)blk*1024*1024;
        const unsigned short* w1_h = W1h + (size_t)blk*4096*1024;
        const unsigned short* w1_l = W1l + (size_t)blk*4096*1024;
        const unsigned short* w2_h = W2h + (size_t)blk*1024*4096;
        const unsigned short* w2_l = W2l + (size_t)blk*1024*4096;

        // LN1 + window partition (+shift): X -> Bh/Bl (window order)
        ln_kernel<<<NTOK / 4, 256, 0, stream>>>(X, ln1g, ln1b, Bh, Bl, shifted, 1);
        // QKV: [12544,1024] x [3072,1024]^T -> QKV fp32
        gemm_mfma<0><<<dim3(3072/128, NTOK/128), 256, 0, stream>>>(
            Bh, Bl, wq_h, wq_l, qkvb, QKV, nullptr, nullptr, 3072, 1024, 0);
        // attention -> Bh/Bl (window order)
        attn_kernel<<<256 * NH, 64, 0, stream>>>(QKV, Bh, Bl, rpb, shifted);
        // proj + window-reverse (+unshift) + residual into X
        gemm_mfma<2><<<dim3(1024/128, NTOK/128), 256, 0, stream>>>(
            Bh, Bl, wp_h, wp_l, projb, X, nullptr, nullptr, 1024, 1024, shifted);
        // LN2: X -> Bh/Bl
        ln_kernel<<<NTOK / 4, 256, 0, stream>>>(X, ln2g, ln2b, Bh, Bl, 0, 0);
        // FC1 + gelu -> Ch/Cl
        gemm_mfma<1><<<dim3(4096/128, NTOK/128), 256, 0, stream>>>(
            Bh, Bl, w1_h, w1_l, fc1b, nullptr, Ch, Cl, 4096, 1024, 0);
        // FC2 + residual into X
        gemm_mfma<3><<<dim3(1024/128, NTOK/128), 256, 0, stream>>>(
            Ch, Cl, w2_h, w2_l, fc2b, X, nullptr, nullptr, 1024, 4096, 0);
    }

    // head
    pool_ln_kernel<<<64, 256, 0, stream>>>(X, P(27), P(28), H0);
    head_gemm_kernel<<<(64 * 512 + 255) / 256, 256, 0, stream>>>(
        H0, P(29), P(30), H1, 64, 1024, 512, 1);
    head_gemm_kernel<<<(64 * 128 + 255) / 256, 256, 0, stream>>>(
        H1, P(31), P(32), H2, 64, 512, 128, 1);
    head_gemm_kernel<<<1, 128, 0, stream>>>(
        H2, P(33), P(34), (float*)d_out, 64, 128, 2, 0);
}

// Round 5
// 2397.833 us; speedup vs baseline: 4.0062x; 1.2796x over previous
//
#include <hip/hip_runtime.h>
#include <hip/hip_bf16.h>
#include <hip/hip_fp16.h>
#include <math.h>

// ---------------- problem constants ----------------
#define BB 64
#define CC 1024
#define NH 32
#define NTOK (BB * 14 * 14)      // 12544
#define SCALE 0.17677669529663687f  // 32^-0.5

typedef __attribute__((ext_vector_type(8))) short short8;
typedef __attribute__((ext_vector_type(8))) unsigned short us8;
typedef __attribute__((ext_vector_type(4))) float f32x4;

// ---------------- static device workspace ----------------
__device__ __align__(16) float  g_X  [(size_t)NTOK * CC];        // residual (fp32)
__device__ __align__(16) float  g_QKV[(size_t)NTOK * 3072];      // qkv out (fp32)
__device__ __align__(16) unsigned short g_B[(size_t)NTOK * CC];   // fp16 acts (1024-wide)
__device__ __align__(16) unsigned short g_C[(size_t)NTOK * 4096]; // fp16 fc1 out
// transposed fp16 weights [N][K]: hi + lo(x2048), 2 blocks each
__device__ __align__(16) unsigned short g_Wq_h[(size_t)2*3072*1024], g_Wq_l[(size_t)2*3072*1024];
__device__ __align__(16) unsigned short g_Wp_h[(size_t)2*1024*1024], g_Wp_l[(size_t)2*1024*1024];
__device__ __align__(16) unsigned short g_W1_h[(size_t)2*4096*1024], g_W1_l[(size_t)2*4096*1024];
__device__ __align__(16) unsigned short g_W2_h[(size_t)2*1024*4096], g_W2_l[(size_t)2*1024*4096];
__device__ __align__(16) float g_H0[64 * CC];
__device__ __align__(16) float g_H1[64 * 512];
__device__ __align__(16) float g_H2[64 * 128];

__device__ __forceinline__ float gelu_f(float x) {
    return 0.5f * x * (1.0f + erff(x * 0.70710678118654752f));
}

// fp16 split: v ~= h + l/2048  (l stored pre-scaled by 2048)
__device__ __forceinline__ void split_f16(float v, unsigned short& h, unsigned short& l) {
    _Float16 hh = (_Float16)v;
    _Float16 ll = (_Float16)((v - (float)hh) * 2048.0f);
    h = *(unsigned short*)&hh;
    l = *(unsigned short*)&ll;
}
__device__ __forceinline__ unsigned short f16_bits(float v) {
    _Float16 hh = (_Float16)v;
    return *(unsigned short*)&hh;
}

// window-order row r (bn*49+t) -> row in X ([B,14,14] flattened)
__device__ __forceinline__ int win_to_xrow(int r, int shifted) {
    int bn = r / 49, t = r - bn * 49;
    int b = bn >> 2, w = bn & 3;
    int wh = w >> 1, ww_ = w & 1;
    int th = t / 7, tw = t - th * 7;
    int gh = wh * 7 + th, gw = ww_ * 7 + tw;
    if (shifted) { gh = gh + 3; if (gh >= 14) gh -= 14; gw = gw + 3; if (gw >= 14) gw -= 14; }
    return b * 196 + gh * 14 + gw;
}

__device__ __forceinline__ void gload_lds16(const void* g, void* l) {
    __builtin_amdgcn_global_load_lds(
        (const __attribute__((address_space(1))) unsigned int*)g,
        (__attribute__((address_space(3))) unsigned int*)l, 16, 0, 0);
}

// ---------------- weight convert + transpose: W[K][N] fp32 -> WT[N][K] fp16 hi/lo
__global__ __launch_bounds__(256) void convw_kernel(const float* __restrict__ W,
    unsigned short* __restrict__ Wh, unsigned short* __restrict__ Wl, int K, int N)
{
    __shared__ float t[32][33];
    int n0 = blockIdx.x * 32, k0 = blockIdx.y * 32;
    int tx = threadIdx.x & 31, ty = threadIdx.x >> 5;
    #pragma unroll
    for (int i = 0; i < 4; ++i)
        t[ty + 8 * i][tx] = W[(size_t)(k0 + ty + 8 * i) * N + n0 + tx];
    __syncthreads();
    #pragma unroll
    for (int i = 0; i < 4; ++i) {
        int n = ty + 8 * i;
        float v = t[tx][n];                 // W[k0+tx][n0+n]
        unsigned short h, l;
        split_f16(v, h, l);
        size_t o = (size_t)(n0 + n) * K + k0 + tx;
        Wh[o] = h; Wl[o] = l;
    }
}

// ---------------- LayerNorm -> fp16 (optional window partition+shift) --------
__global__ __launch_bounds__(256) void ln_kernel(const float* __restrict__ X,
    const float* __restrict__ g, const float* __restrict__ bta,
    unsigned short* __restrict__ outh, int shifted, int partition)
{
    int token = blockIdx.x * 4 + (threadIdx.x >> 6);
    int lane = threadIdx.x & 63;
    int xrow = partition ? win_to_xrow(token, shifted) : token;
    const float4* src = (const float4*)(X + (size_t)xrow * CC);
    float4 v[4];
    float s = 0.f;
    #pragma unroll
    for (int w = 0; w < 4; ++w) {
        v[w] = src[w * 64 + lane];
        s += v[w].x + v[w].y + v[w].z + v[w].w;
    }
    #pragma unroll
    for (int o = 32; o; o >>= 1) s += __shfl_xor(s, o);
    float mean = s * (1.0f / CC);
    float ss = 0.f;
    #pragma unroll
    for (int w = 0; w < 4; ++w) {
        float d0 = v[w].x - mean, d1 = v[w].y - mean, d2 = v[w].z - mean, d3 = v[w].w - mean;
        ss += d0 * d0 + d1 * d1 + d2 * d2 + d3 * d3;
    }
    #pragma unroll
    for (int o = 32; o; o >>= 1) ss += __shfl_xor(ss, o);
    float inv = 1.0f / sqrtf(ss * (1.0f / CC) + 1e-5f);
    #pragma unroll
    for (int w = 0; w < 4; ++w) {
        int c4 = w * 64 + lane;
        float4 gv = *(const float4*)(g + c4 * 4);
        float4 bv = *(const float4*)(bta + c4 * 4);
        ushort4 uo;
        uo.x = f16_bits((v[w].x - mean) * inv * gv.x + bv.x);
        uo.y = f16_bits((v[w].y - mean) * inv * gv.y + bv.y);
        uo.z = f16_bits((v[w].z - mean) * inv * gv.z + bv.z);
        uo.w = f16_bits((v[w].w - mean) * inv * gv.w + bv.w);
        *(ushort4*)(outh + (size_t)token * CC + c4 * 4) = uo;
    }
}

// ---------------- fp16-x2 MFMA GEMM: C = A[M][K] * (Wh + Wl/2048)[N][K]^T ----
// 128x128 tile, BK=64, 4 waves (2x2), 4x4 16x16x32 frags/wave, 64 MFMA/wave/K-tile.
// 3 LDS tiles [128][64] fp16 (A, Wh, Wl) = 48KB, XOR swizzle slot^=row&7 both sides.
// Grid: 1D with bijective XCD swizzle + col-group supertile (GC cols x NR rows).
// EPI: 0 fp32 store+bias (QKV); 1 gelu -> fp16 store, LDS-coalesced (FC1);
//      2 residual += into X via window map (proj); 3 residual += direct (FC2)
template<int EPI>
__global__ __launch_bounds__(256, 2) void gemm_mfma(
    const unsigned short* __restrict__ A,
    const unsigned short* __restrict__ Wh, const unsigned short* __restrict__ Wl,
    const float* __restrict__ bias,
    float* __restrict__ outf, unsigned short* __restrict__ outh,
    int N, int K, int shifted, int NR, int GC)
{
    __shared__ unsigned short sm[24576];   // 3 tiles x [128][64] fp16, 16KB each
    const int tid = threadIdx.x;
    const int wave = tid >> 6, lane = tid & 63;
    const int wr = wave >> 1, wc = wave & 1;
    // ---- grid remap: XCD chunk + col-group supertile
    const int nb = gridDim.x;
    const int wg = (blockIdx.x & 7) * (nb >> 3) + (blockIdx.x >> 3);
    const int gsz = GC * NR;
    const int grp = wg / gsz;
    const int rem = wg - grp * gsz;
    const int by = rem / GC;
    const int bx = grp * GC + (rem - by * GC);
    const int row0 = by * 128, col0 = bx * 128;
    const int rsel = lane & 15;

    f32x4 acc1[4][4] = {};
    f32x4 acc2[4][4] = {};

    const int srow = tid >> 3, sslot = tid & 7;

    for (int k0 = 0; k0 < K; k0 += 64) {
        // ---- stage 3 tiles via global_load_lds (linear dest, swizzled source)
        #pragma unroll
        for (int i = 0; i < 12; ++i) {
            const int t = i >> 2;               // tile id 0..2 (compile-time)
            const int sub = i & 3;              // 32-row group
            const int row = sub * 32 + srow;
            const int c = sslot ^ (row & 7);    // global k-chunk for this slot
            const unsigned short* gp = (t == 0) ? A : (t == 1) ? Wh : Wl;
            const int rb = (t == 0) ? row0 : col0;
            gload_lds16(gp + (size_t)(rb + row) * K + k0 + c * 8,
                        &sm[t * 8192 + sub * 2048 + tid * 8]);
        }
        __syncthreads();

        // ---- per 32-K step: 12 ds_read_b128 + 32 MFMA
        #pragma unroll
        for (int kk = 0; kk < 2; ++kk) {
            const int kc8 = kk * 4 + (lane >> 4);
            short8 fa[4], fh[4], fl[4];
            #pragma unroll
            for (int m = 0; m < 4; ++m) {
                int ra = wr * 64 + m * 16 + rsel;
                fa[m] = *(const short8*)&sm[ra * 64 + ((kc8 ^ (ra & 7)) * 8)];
                int rw = wc * 64 + m * 16 + rsel;
                int ow = rw * 64 + ((kc8 ^ (rw & 7)) * 8);
                fh[m] = *(const short8*)&sm[8192 + ow];
                fl[m] = *(const short8*)&sm[16384 + ow];
            }
            #pragma unroll
            for (int m = 0; m < 4; ++m)
                #pragma unroll
                for (int n = 0; n < 4; ++n) {
                    acc1[m][n] = __builtin_amdgcn_mfma_f32_16x16x32_f16(fa[m], fh[n], acc1[m][n], 0, 0, 0);
                    acc2[m][n] = __builtin_amdgcn_mfma_f32_16x16x32_f16(fa[m], fl[n], acc2[m][n], 0, 0, 0);
                }
        }
        __syncthreads();
    }

    // ---- epilogue: D layout col=lane&15, row=(lane>>4)*4+j
    const int jrow = lane >> 4;
    if (EPI == 1) {
        // write tile into LDS as fp16, then stream coalesced
        #pragma unroll
        for (int n = 0; n < 4; ++n) {
            int cl = wc * 64 + n * 16 + rsel;
            float bv = bias[col0 + cl];
            #pragma unroll
            for (int m = 0; m < 4; ++m)
                #pragma unroll
                for (int j = 0; j < 4; ++j) {
                    int rl = wr * 64 + m * 16 + jrow * 4 + j;
                    float v = acc1[m][n][j] + acc2[m][n][j] * (1.0f / 2048.0f) + bv;
                    sm[rl * 128 + cl] = f16_bits(gelu_f(v));
                }
        }
        __syncthreads();
        const int r = tid >> 1, cb = (tid & 1) * 64;
        unsigned short* dst = outh + (size_t)(row0 + r) * N + col0 + cb;
        const unsigned short* src = &sm[r * 128 + cb];
        #pragma unroll
        for (int i = 0; i < 8; ++i)
            *(us8*)(dst + i * 8) = *(const us8*)(src + i * 8);
    } else {
        #pragma unroll
        for (int n = 0; n < 4; ++n) {
            int c = col0 + wc * 64 + n * 16 + rsel;
            float bv = bias[c];
            #pragma unroll
            for (int m = 0; m < 4; ++m) {
                #pragma unroll
                for (int j = 0; j < 4; ++j) {
                    int r = row0 + wr * 64 + m * 16 + jrow * 4 + j;
                    float v = acc1[m][n][j] + acc2[m][n][j] * (1.0f / 2048.0f) + bv;
                    if (EPI == 0) {
                        outf[(size_t)r * N + c] = v;
                    } else if (EPI == 2) {
                        outf[(size_t)win_to_xrow(r, shifted) * CC + c] += v;
                    } else {
                        outf[(size_t)r * CC + c] += v;
                    }
                }
            }
        }
    }
}

// ---------------- windowed attention (fp32 math, fp16 out) -------------------
__global__ __launch_bounds__(64) void attn_kernel(const float* __restrict__ qkv,
    unsigned short* __restrict__ oh, const float* __restrict__ rpb, int shifted)
{
    int bh = blockIdx.x;
    int bn = bh >> 5, h = bh & 31;
    __shared__ float qs[49][32], ks[49][32], vs[49][32];
    __shared__ float ss[49][50];
    int lane = threadIdx.x;
    for (int idx = lane; idx < 49 * 32; idx += 64) {
        int t = idx >> 5, d = idx & 31;
        const float* p = qkv + (size_t)(bn * 49 + t) * 3072 + h * 32 + d;
        qs[t][d] = p[0];
        ks[t][d] = p[1024];
        vs[t][d] = p[2048];
    }
    __syncthreads();
    if (lane < 49) {
        int i = lane;
        int ih = i / 7, iw = i - ih * 7;
        int w = bn & 3, wh = w >> 1, ww_ = w & 1;
        int gh = wh * 7 + ih, gw = ww_ * 7 + iw;
        int li = (gh < 7 ? 0 : (gh < 11 ? 1 : 2)) * 3 + (gw < 7 ? 0 : (gw < 11 ? 1 : 2));
        float qreg[32];
        #pragma unroll
        for (int d = 0; d < 32; ++d) qreg[d] = qs[i][d] * SCALE;
        float mx = -1e30f;
        for (int j = 0; j < 49; ++j) {
            int jh = j / 7, jw = j - jh * 7;
            float dot = 0.f;
            #pragma unroll
            for (int d = 0; d < 32; ++d) dot = fmaf(qreg[d], ks[j][d], dot);
            int ridx = (ih - jh + 6) * 13 + (iw - jw + 6);
            float val = dot + rpb[ridx * 32 + h];
            if (shifted) {
                int gjh = wh * 7 + jh, gjw = ww_ * 7 + jw;
                int lj = (gjh < 7 ? 0 : (gjh < 11 ? 1 : 2)) * 3 +
                         (gjw < 7 ? 0 : (gjw < 11 ? 1 : 2));
                if (li != lj) val -= 100.0f;
            }
            ss[i][j] = val;
            mx = fmaxf(mx, val);
        }
        float denom = 0.f;
        for (int j = 0; j < 49; ++j) {
            float e = expf(ss[i][j] - mx);
            ss[i][j] = e;
            denom += e;
        }
        float rd = 1.0f / denom;
        size_t obase = (size_t)(bn * 49 + i) * CC + h * 32;
        #pragma unroll 4
        for (int d = 0; d < 32; ++d) {
            float acc = 0.f;
            for (int j = 0; j < 49; ++j) acc = fmaf(ss[i][j], vs[j][d], acc);
            oh[obase + d] = f16_bits(acc * rd);
        }
    }
}

// ---------------- global-avg-pool + LayerNorm --------------------------------
__global__ __launch_bounds__(256) void pool_ln_kernel(const float* __restrict__ X,
    const float* __restrict__ g, const float* __restrict__ bta, float* __restrict__ out)
{
    int b = blockIdx.x, tid = threadIdx.x;
    int lane = tid & 63, wid = tid >> 6;
    const float* base = X + (size_t)b * 196 * CC + tid * 4;
    float a0 = 0, a1 = 0, a2 = 0, a3 = 0;
    for (int t = 0; t < 196; ++t) {
        float4 v = *(const float4*)(base + (size_t)t * CC);
        a0 += v.x; a1 += v.y; a2 += v.z; a3 += v.w;
    }
    const float inv196 = 1.0f / 196.0f;
    float p0 = a0 * inv196, p1 = a1 * inv196, p2 = a2 * inv196, p3 = a3 * inv196;
    float s = p0 + p1 + p2 + p3;
    #pragma unroll
    for (int o = 32; o; o >>= 1) s += __shfl_xor(s, o);
    __shared__ float sred[4], ssred[4];
    if (lane == 0) sred[wid] = s;
    __syncthreads();
    float mean = (sred[0] + sred[1] + sred[2] + sred[3]) * (1.0f / CC);
    float d0 = p0 - mean, d1 = p1 - mean, d2 = p2 - mean, d3 = p3 - mean;
    float ss = d0 * d0 + d1 * d1 + d2 * d2 + d3 * d3;
    #pragma unroll
    for (int o = 32; o; o >>= 1) ss += __shfl_xor(ss, o);
    if (lane == 0) ssred[wid] = ss;
    __syncthreads();
    float var = (ssred[0] + ssred[1] + ssred[2] + ssred[3]) * (1.0f / CC);
    float inv = 1.0f / sqrtf(var + 1e-5f);
    float4 gv = *(const float4*)(g + tid * 4);
    float4 bv = *(const float4*)(bta + tid * 4);
    float4 o4;
    o4.x = d0 * inv * gv.x + bv.x;
    o4.y = d1 * inv * gv.y + bv.y;
    o4.z = d2 * inv * gv.z + bv.z;
    o4.w = d3 * inv * gv.w + bv.w;
    *(float4*)(out + (size_t)b * CC + tid * 4) = o4;
}

// ---------------- head GEMM: one block per row, A row in LDS -----------------
__global__ __launch_bounds__(256) void head_rowgemm(const float* __restrict__ A,
    const float* __restrict__ W, const float* __restrict__ bias,
    float* __restrict__ out, int K, int N, int act)
{
    __shared__ float As[1024];
    int r = blockIdx.x, tid = threadIdx.x;
    for (int k = tid; k < K; k += 256) As[k] = A[(size_t)r * K + k];
    __syncthreads();
    for (int c = tid; c < N; c += 256) {
        float s0 = 0.f, s1 = 0.f;
        for (int k = 0; k < K; k += 2) {
            s0 = fmaf(As[k],     W[(size_t)k * N + c],       s0);
            s1 = fmaf(As[k + 1], W[(size_t)(k + 1) * N + c], s1);
        }
        float s = s0 + s1 + bias[c];
        out[(size_t)r * N + c] = act ? gelu_f(s) : s;
    }
}

// ---------------- launch ------------------------------------------------------
extern "C" void kernel_launch(void* const* d_in, const int* in_sizes, int n_in,
                              void* d_out, int out_size, void* d_ws, size_t ws_size,
                              hipStream_t stream) {
    const float* x = (const float*)d_in[0];
    auto P = [&](int i) { return (const float*)d_in[i]; };

    float *X, *QKV, *H0, *H1, *H2;
    unsigned short *B, *C;
    unsigned short *Wqh, *Wql, *Wph, *Wpl, *W1h, *W1l, *W2h, *W2l;
    { void* p;
      hipGetSymbolAddress(&p, HIP_SYMBOL(g_X));   X   = (float*)p;
      hipGetSymbolAddress(&p, HIP_SYMBOL(g_QKV)); QKV = (float*)p;
      hipGetSymbolAddress(&p, HIP_SYMBOL(g_B));   B   = (unsigned short*)p;
      hipGetSymbolAddress(&p, HIP_SYMBOL(g_C));   C   = (unsigned short*)p;
      hipGetSymbolAddress(&p, HIP_SYMBOL(g_Wq_h)); Wqh = (unsigned short*)p;
      hipGetSymbolAddress(&p, HIP_SYMBOL(g_Wq_l)); Wql = (unsigned short*)p;
      hipGetSymbolAddress(&p, HIP_SYMBOL(g_Wp_h)); Wph = (unsigned short*)p;
      hipGetSymbolAddress(&p, HIP_SYMBOL(g_Wp_l)); Wpl = (unsigned short*)p;
      hipGetSymbolAddress(&p, HIP_SYMBOL(g_W1_h)); W1h = (unsigned short*)p;
      hipGetSymbolAddress(&p, HIP_SYMBOL(g_W1_l)); W1l = (unsigned short*)p;
      hipGetSymbolAddress(&p, HIP_SYMBOL(g_W2_h)); W2h = (unsigned short*)p;
      hipGetSymbolAddress(&p, HIP_SYMBOL(g_W2_l)); W2l = (unsigned short*)p;
      hipGetSymbolAddress(&p, HIP_SYMBOL(g_H0));  H0 = (float*)p;
      hipGetSymbolAddress(&p, HIP_SYMBOL(g_H1));  H1 = (float*)p;
      hipGetSymbolAddress(&p, HIP_SYMBOL(g_H2));  H2 = (float*)p;
    }

    hipMemcpyAsync(X, x, (size_t)NTOK * CC * sizeof(float),
                   hipMemcpyDeviceToDevice, stream);

    // weight conversion + transpose (per launch; weights are inputs)
    for (int blk = 0; blk < 2; ++blk) {
        int base = 1 + blk * 13;
        convw_kernel<<<dim3(3072/32, 1024/32), 256, 0, stream>>>(
            P(base + 2), Wqh + (size_t)blk*3072*1024, Wql + (size_t)blk*3072*1024, 1024, 3072);
        convw_kernel<<<dim3(1024/32, 1024/32), 256, 0, stream>>>(
            P(base + 5), Wph + (size_t)blk*1024*1024, Wpl + (size_t)blk*1024*1024, 1024, 1024);
        convw_kernel<<<dim3(4096/32, 1024/32), 256, 0, stream>>>(
            P(base + 9), W1h + (size_t)blk*4096*1024, W1l + (size_t)blk*4096*1024, 1024, 4096);
        convw_kernel<<<dim3(1024/32, 4096/32), 256, 0, stream>>>(
            P(base + 11), W2h + (size_t)blk*1024*4096, W2l + (size_t)blk*1024*4096, 4096, 1024);
    }

    for (int blk = 0; blk < 2; ++blk) {
        int base = 1 + blk * 13;
        const float *ln1g = P(base + 0), *ln1b = P(base + 1);
        const float *qkvb = P(base + 3);
        const float *rpb  = P(base + 4);
        const float *projb = P(base + 6);
        const float *ln2g = P(base + 7), *ln2b = P(base + 8);
        const float *fc1b = P(base + 10);
        const float *fc2b = P(base + 12);
        int shifted = blk;
        const unsigned short* wq_h = Wqh + (size_t)blk*3072*1024;
        const unsigned short* wq_l = Wql + (size_t)blk*3072*1024;
        const unsigned short* wp_h = Wph + (size_t)blk*1024*1024;
        const unsigned short* wp_l = Wpl + (size_t)blk*1024*1024;
        const unsigned short* w1_h = W1h + (size_t)blk*4096*1024;
        const unsigned short* w1_l = W1l + (size_t)blk*4096*1024;
        const unsigned short* w2_h = W2h + (size_t)blk*1024*4096;
        const unsigned short* w2_l = W2l + (size_t)blk*1024*4096;

        // LN1 + window partition (+shift): X -> B (fp16, window order)
        ln_kernel<<<NTOK / 4, 256, 0, stream>>>(X, ln1g, ln1b, B, shifted, 1);
        // QKV: [12544,1024] x [3072,1024]^T -> QKV fp32   (grid 2352, GC=8)
        gemm_mfma<0><<<2352, 256, 0, stream>>>(
            B, wq_h, wq_l, qkvb, QKV, nullptr, 3072, 1024, 0, 98, 8);
        // attention -> B (fp16, window order)
        attn_kernel<<<256 * NH, 64, 0, stream>>>(QKV, B, rpb, shifted);
        // proj + window-reverse (+unshift) + residual into X (grid 784, GC=8)
        gemm_mfma<2><<<784, 256, 0, stream>>>(
            B, wp_h, wp_l, projb, X, nullptr, 1024, 1024, shifted, 98, 8);
        // LN2: X -> B
        ln_kernel<<<NTOK / 4, 256, 0, stream>>>(X, ln2g, ln2b, B, 0, 0);
        // FC1 + gelu -> C (fp16)  (grid 3136, GC=8)
        gemm_mfma<1><<<3136, 256, 0, stream>>>(
            B, w1_h, w1_l, fc1b, nullptr, C, 4096, 1024, 0, 98, 8);
        // FC2 + residual into X   (grid 784, GC=2: W-set fits per-XCD L2)
        gemm_mfma<3><<<784, 256, 0, stream>>>(
            C, w2_h, w2_l, fc2b, X, nullptr, 1024, 4096, 0, 98, 2);
    }

    // head
    pool_ln_kernel<<<64, 256, 0, stream>>>(X, P(27), P(28), H0);
    head_rowgemm<<<64, 256, 0, stream>>>(H0, P(29), P(30), H1, 1024, 512, 1);
    head_rowgemm<<<64, 256, 0, stream>>>(H1, P(31), P(32), H2, 512, 128, 1);
    head_rowgemm<<<64, 256, 0, stream>>>(H2, P(33), P(34), (float*)d_out, 128, 2, 0);
}

// Round 6
// 1502.416 us; speedup vs baseline: 6.3938x; 1.5960x over previous
//
#include <hip/hip_runtime.h>
#include <hip/hip_bf16.h>
#include <hip/hip_fp16.h>
#include <math.h>

// ---------------- problem constants ----------------
#define BB 64
#define CC 1024
#define NH 32
#define NTOK (BB * 14 * 14)      // 12544
#define SCALE 0.17677669529663687f  // 32^-0.5

typedef __attribute__((ext_vector_type(8))) short short8;
typedef __attribute__((ext_vector_type(8))) unsigned short us8;
typedef __attribute__((ext_vector_type(4))) float f32x4;

// ---------------- static device workspace ----------------
__device__ __align__(16) float  g_X  [(size_t)NTOK * CC];        // residual (fp32)
__device__ __align__(16) float  g_QKV[(size_t)NTOK * 3072];      // qkv out (fp32)
__device__ __align__(16) unsigned short g_B[(size_t)NTOK * CC];   // fp16 acts (1024-wide)
__device__ __align__(16) unsigned short g_C[(size_t)NTOK * 4096]; // fp16 fc1 out
// transposed fp16 weights [N][K], 2 blocks each
__device__ __align__(16) unsigned short g_Wq[(size_t)2*3072*1024];
__device__ __align__(16) unsigned short g_Wp[(size_t)2*1024*1024];
__device__ __align__(16) unsigned short g_W1[(size_t)2*4096*1024];
__device__ __align__(16) unsigned short g_W2[(size_t)2*1024*4096];
__device__ __align__(16) float g_H0[64 * CC];
__device__ __align__(16) float g_H1[64 * 512];
__device__ __align__(16) float g_H2[64 * 128];

__device__ __forceinline__ float gelu_f(float x) {
    return 0.5f * x * (1.0f + erff(x * 0.70710678118654752f));
}

__device__ __forceinline__ unsigned short f16_bits(float v) {
    _Float16 hh = (_Float16)v;
    return *(unsigned short*)&hh;
}

// window-order row r (bn*49+t) -> row in X ([B,14,14] flattened)
__device__ __forceinline__ int win_to_xrow(int r, int shifted) {
    int bn = r / 49, t = r - bn * 49;
    int b = bn >> 2, w = bn & 3;
    int wh = w >> 1, ww_ = w & 1;
    int th = t / 7, tw = t - th * 7;
    int gh = wh * 7 + th, gw = ww_ * 7 + tw;
    if (shifted) { gh = gh + 3; if (gh >= 14) gh -= 14; gw = gw + 3; if (gw >= 14) gw -= 14; }
    return b * 196 + gh * 14 + gw;
}

__device__ __forceinline__ void gload_lds16(const void* g, void* l) {
    __builtin_amdgcn_global_load_lds(
        (const __attribute__((address_space(1))) unsigned int*)g,
        (__attribute__((address_space(3))) unsigned int*)l, 16, 0, 0);
}

// ---------------- weight convert + transpose: W[K][N] fp32 -> WT[N][K] fp16 --
__global__ __launch_bounds__(256) void convw_kernel(const float* __restrict__ W,
    unsigned short* __restrict__ Wh, int K, int N)
{
    __shared__ float t[32][33];
    int n0 = blockIdx.x * 32, k0 = blockIdx.y * 32;
    int tx = threadIdx.x & 31, ty = threadIdx.x >> 5;
    #pragma unroll
    for (int i = 0; i < 4; ++i)
        t[ty + 8 * i][tx] = W[(size_t)(k0 + ty + 8 * i) * N + n0 + tx];
    __syncthreads();
    #pragma unroll
    for (int i = 0; i < 4; ++i) {
        int n = ty + 8 * i;
        Wh[(size_t)(n0 + n) * K + k0 + tx] = f16_bits(t[tx][n]);
    }
}

// ---------------- LayerNorm -> fp16 (optional window partition+shift) --------
__global__ __launch_bounds__(256) void ln_kernel(const float* __restrict__ X,
    const float* __restrict__ g, const float* __restrict__ bta,
    unsigned short* __restrict__ outh, int shifted, int partition)
{
    int token = blockIdx.x * 4 + (threadIdx.x >> 6);
    int lane = threadIdx.x & 63;
    int xrow = partition ? win_to_xrow(token, shifted) : token;
    const float4* src = (const float4*)(X + (size_t)xrow * CC);
    float4 v[4];
    float s = 0.f;
    #pragma unroll
    for (int w = 0; w < 4; ++w) {
        v[w] = src[w * 64 + lane];
        s += v[w].x + v[w].y + v[w].z + v[w].w;
    }
    #pragma unroll
    for (int o = 32; o; o >>= 1) s += __shfl_xor(s, o);
    float mean = s * (1.0f / CC);
    float ss = 0.f;
    #pragma unroll
    for (int w = 0; w < 4; ++w) {
        float d0 = v[w].x - mean, d1 = v[w].y - mean, d2 = v[w].z - mean, d3 = v[w].w - mean;
        ss += d0 * d0 + d1 * d1 + d2 * d2 + d3 * d3;
    }
    #pragma unroll
    for (int o = 32; o; o >>= 1) ss += __shfl_xor(ss, o);
    float inv = 1.0f / sqrtf(ss * (1.0f / CC) + 1e-5f);
    #pragma unroll
    for (int w = 0; w < 4; ++w) {
        int c4 = w * 64 + lane;
        float4 gv = *(const float4*)(g + c4 * 4);
        float4 bv = *(const float4*)(bta + c4 * 4);
        ushort4 uo;
        uo.x = f16_bits((v[w].x - mean) * inv * gv.x + bv.x);
        uo.y = f16_bits((v[w].y - mean) * inv * gv.y + bv.y);
        uo.z = f16_bits((v[w].z - mean) * inv * gv.z + bv.z);
        uo.w = f16_bits((v[w].w - mean) * inv * gv.w + bv.w);
        *(ushort4*)(outh + (size_t)token * CC + c4 * 4) = uo;
    }
}

// ---------------- fp16 MFMA GEMM: C = A[M][K] * W[N][K]^T --------------------
// 128x128 tile, BK=64, 4 waves (2x2), 4x4 16x16x32 frags/wave, 32 MFMA/wave/K-tile.
// 2 LDS tiles [128][64] fp16 (A, W) = 32KB, XOR swizzle slot^=row&7 both sides.
// Grid: 1D with XCD chunking + col-group supertile (GC cols x NR rows).
// EPI: 0 fp32 store+bias (QKV); 1 gelu -> fp16 store, LDS-coalesced (FC1);
//      2 residual += into X via window map (proj); 3 residual += direct (FC2)
template<int EPI>
__global__ __launch_bounds__(256, 2) void gemm_mfma(
    const unsigned short* __restrict__ A, const unsigned short* __restrict__ W,
    const float* __restrict__ bias,
    float* __restrict__ outf, unsigned short* __restrict__ outh,
    int N, int K, int shifted, int NR, int GC)
{
    __shared__ unsigned short sm[16896];   // 2 staging tiles (32KB) / epi tile 128x132
    const int tid = threadIdx.x;
    const int wave = tid >> 6, lane = tid & 63;
    const int wr = wave >> 1, wc = wave & 1;
    // ---- grid remap: XCD chunk + col-group supertile
    const int nb = gridDim.x;
    const int wg = (blockIdx.x & 7) * (nb >> 3) + (blockIdx.x >> 3);
    const int gsz = GC * NR;
    const int grp = wg / gsz;
    const int rem = wg - grp * gsz;
    const int by = rem / GC;
    const int bx = grp * GC + (rem - by * GC);
    const int row0 = by * 128, col0 = bx * 128;
    const int rsel = lane & 15;

    f32x4 acc[4][4] = {};

    const int srow = tid >> 3, sslot = tid & 7;

    for (int k0 = 0; k0 < K; k0 += 64) {
        // ---- stage 2 tiles via global_load_lds (linear dest, swizzled source)
        #pragma unroll
        for (int i = 0; i < 8; ++i) {
            const int t = i >> 2;               // tile id 0..1 (compile-time)
            const int sub = i & 3;              // 32-row group
            const int row = sub * 32 + srow;
            const int c = sslot ^ (row & 7);    // global k-chunk for this slot
            const unsigned short* gp = (t == 0) ? A : W;
            const int rb = (t == 0) ? row0 : col0;
            gload_lds16(gp + (size_t)(rb + row) * K + k0 + c * 8,
                        &sm[t * 8192 + sub * 2048 + tid * 8]);
        }
        __syncthreads();

        // ---- per 32-K step: 8 ds_read_b128 + 16 MFMA
        #pragma unroll
        for (int kk = 0; kk < 2; ++kk) {
            const int kc8 = kk * 4 + (lane >> 4);
            short8 fa[4], fw[4];
            #pragma unroll
            for (int m = 0; m < 4; ++m) {
                int ra = wr * 64 + m * 16 + rsel;
                fa[m] = *(const short8*)&sm[ra * 64 + ((kc8 ^ (ra & 7)) * 8)];
                int rw = wc * 64 + m * 16 + rsel;
                fw[m] = *(const short8*)&sm[8192 + rw * 64 + ((kc8 ^ (rw & 7)) * 8)];
            }
            #pragma unroll
            for (int m = 0; m < 4; ++m)
                #pragma unroll
                for (int n = 0; n < 4; ++n)
                    acc[m][n] = __builtin_amdgcn_mfma_f32_16x16x32_f16(fa[m], fw[n], acc[m][n], 0, 0, 0);
        }
        __syncthreads();
    }

    // ---- epilogue: D layout col=lane&15, row=(lane>>4)*4+j
    const int jrow = lane >> 4;
    if (EPI == 1) {
        // write tile into LDS (stride 132: conflict-free), then stream coalesced
        #pragma unroll
        for (int n = 0; n < 4; ++n) {
            int cl = wc * 64 + n * 16 + rsel;
            float bv = bias[col0 + cl];
            #pragma unroll
            for (int m = 0; m < 4; ++m)
                #pragma unroll
                for (int j = 0; j < 4; ++j) {
                    int rl = wr * 64 + m * 16 + jrow * 4 + j;
                    sm[rl * 132 + cl] = f16_bits(gelu_f(acc[m][n][j] + bv));
                }
        }
        __syncthreads();
        const int r = tid >> 1, cb = (tid & 1) * 64;
        unsigned short* dst = outh + (size_t)(row0 + r) * N + col0 + cb;
        const unsigned short* src = &sm[r * 132 + cb];
        #pragma unroll
        for (int i = 0; i < 8; ++i)
            *(us8*)(dst + i * 8) = *(const us8*)(src + i * 8);
    } else {
        #pragma unroll
        for (int n = 0; n < 4; ++n) {
            int c = col0 + wc * 64 + n * 16 + rsel;
            float bv = bias[c];
            #pragma unroll
            for (int m = 0; m < 4; ++m) {
                #pragma unroll
                for (int j = 0; j < 4; ++j) {
                    int r = row0 + wr * 64 + m * 16 + jrow * 4 + j;
                    float v = acc[m][n][j] + bv;
                    if (EPI == 0) {
                        outf[(size_t)r * N + c] = v;
                    } else if (EPI == 2) {
                        outf[(size_t)win_to_xrow(r, shifted) * CC + c] += v;
                    } else {
                        outf[(size_t)r * CC + c] += v;
                    }
                }
            }
        }
    }
}

// ---------------- windowed attention (fp32 math, fp16 out) -------------------
__global__ __launch_bounds__(64) void attn_kernel(const float* __restrict__ qkv,
    unsigned short* __restrict__ oh, const float* __restrict__ rpb, int shifted)
{
    int bh = blockIdx.x;
    int bn = bh >> 5, h = bh & 31;
    __shared__ float qs[49][32], ks[49][32], vs[49][32];
    __shared__ float ss[49][50];
    int lane = threadIdx.x;
    for (int idx = lane; idx < 49 * 32; idx += 64) {
        int t = idx >> 5, d = idx & 31;
        const float* p = qkv + (size_t)(bn * 49 + t) * 3072 + h * 32 + d;
        qs[t][d] = p[0];
        ks[t][d] = p[1024];
        vs[t][d] = p[2048];
    }
    __syncthreads();
    if (lane < 49) {
        int i = lane;
        int ih = i / 7, iw = i - ih * 7;
        int w = bn & 3, wh = w >> 1, ww_ = w & 1;
        int gh = wh * 7 + ih, gw = ww_ * 7 + iw;
        int li = (gh < 7 ? 0 : (gh < 11 ? 1 : 2)) * 3 + (gw < 7 ? 0 : (gw < 11 ? 1 : 2));
        float qreg[32];
        #pragma unroll
        for (int d = 0; d < 32; ++d) qreg[d] = qs[i][d] * SCALE;
        float mx = -1e30f;
        for (int j = 0; j < 49; ++j) {
            int jh = j / 7, jw = j - jh * 7;
            float dot = 0.f;
            #pragma unroll
            for (int d = 0; d < 32; ++d) dot = fmaf(qreg[d], ks[j][d], dot);
            int ridx = (ih - jh + 6) * 13 + (iw - jw + 6);
            float val = dot + rpb[ridx * 32 + h];
            if (shifted) {
                int gjh = wh * 7 + jh, gjw = ww_ * 7 + jw;
                int lj = (gjh < 7 ? 0 : (gjh < 11 ? 1 : 2)) * 3 +
                         (gjw < 7 ? 0 : (gjw < 11 ? 1 : 2));
                if (li != lj) val -= 100.0f;
            }
            ss[i][j] = val;
            mx = fmaxf(mx, val);
        }
        float denom = 0.f;
        for (int j = 0; j < 49; ++j) {
            float e = expf(ss[i][j] - mx);
            ss[i][j] = e;
            denom += e;
        }
        float rd = 1.0f / denom;
        size_t obase = (size_t)(bn * 49 + i) * CC + h * 32;
        #pragma unroll 4
        for (int d = 0; d < 32; ++d) {
            float acc = 0.f;
            for (int j = 0; j < 49; ++j) acc = fmaf(ss[i][j], vs[j][d], acc);
            oh[obase + d] = f16_bits(acc * rd);
        }
    }
}

// ---------------- global-avg-pool + LayerNorm --------------------------------
__global__ __launch_bounds__(256) void pool_ln_kernel(const float* __restrict__ X,
    const float* __restrict__ g, const float* __restrict__ bta, float* __restrict__ out)
{
    int b = blockIdx.x, tid = threadIdx.x;
    int lane = tid & 63, wid = tid >> 6;
    const float* base = X + (size_t)b * 196 * CC + tid * 4;
    float a0 = 0, a1 = 0, a2 = 0, a3 = 0;
    for (int t = 0; t < 196; ++t) {
        float4 v = *(const float4*)(base + (size_t)t * CC);
        a0 += v.x; a1 += v.y; a2 += v.z; a3 += v.w;
    }
    const float inv196 = 1.0f / 196.0f;
    float p0 = a0 * inv196, p1 = a1 * inv196, p2 = a2 * inv196, p3 = a3 * inv196;
    float s = p0 + p1 + p2 + p3;
    #pragma unroll
    for (int o = 32; o; o >>= 1) s += __shfl_xor(s, o);
    __shared__ float sred[4], ssred[4];
    if (lane == 0) sred[wid] = s;
    __syncthreads();
    float mean = (sred[0] + sred[1] + sred[2] + sred[3]) * (1.0f / CC);
    float d0 = p0 - mean, d1 = p1 - mean, d2 = p2 - mean, d3 = p3 - mean;
    float ss = d0 * d0 + d1 * d1 + d2 * d2 + d3 * d3;
    #pragma unroll
    for (int o = 32; o; o >>= 1) ss += __shfl_xor(ss, o);
    if (lane == 0) ssred[wid] = ss;
    __syncthreads();
    float var = (ssred[0] + ssred[1] + ssred[2] + ssred[3]) * (1.0f / CC);
    float inv = 1.0f / sqrtf(var + 1e-5f);
    float4 gv = *(const float4*)(g + tid * 4);
    float4 bv = *(const float4*)(bta + tid * 4);
    float4 o4;
    o4.x = d0 * inv * gv.x + bv.x;
    o4.y = d1 * inv * gv.y + bv.y;
    o4.z = d2 * inv * gv.z + bv.z;
    o4.w = d3 * inv * gv.w + bv.w;
    *(float4*)(out + (size_t)b * CC + tid * 4) = o4;
}

// ---------------- head GEMM: one block per row, A row in LDS -----------------
__global__ __launch_bounds__(256) void head_rowgemm(const float* __restrict__ A,
    const float* __restrict__ W, const float* __restrict__ bias,
    float* __restrict__ out, int K, int N, int act)
{
    __shared__ float As[1024];
    int r = blockIdx.x, tid = threadIdx.x;
    for (int k = tid; k < K; k += 256) As[k] = A[(size_t)r * K + k];
    __syncthreads();
    for (int c = tid; c < N; c += 256) {
        float s0 = 0.f, s1 = 0.f;
        for (int k = 0; k < K; k += 2) {
            s0 = fmaf(As[k],     W[(size_t)k * N + c],       s0);
            s1 = fmaf(As[k + 1], W[(size_t)(k + 1) * N + c], s1);
        }
        float s = s0 + s1 + bias[c];
        out[(size_t)r * N + c] = act ? gelu_f(s) : s;
    }
}

// ---------------- launch ------------------------------------------------------
extern "C" void kernel_launch(void* const* d_in, const int* in_sizes, int n_in,
                              void* d_out, int out_size, void* d_ws, size_t ws_size,
                              hipStream_t stream) {
    const float* x = (const float*)d_in[0];
    auto P = [&](int i) { return (const float*)d_in[i]; };

    float *X, *QKV, *H0, *H1, *H2;
    unsigned short *B, *C, *Wq, *Wp, *W1, *W2;
    { void* p;
      hipGetSymbolAddress(&p, HIP_SYMBOL(g_X));   X   = (float*)p;
      hipGetSymbolAddress(&p, HIP_SYMBOL(g_QKV)); QKV = (float*)p;
      hipGetSymbolAddress(&p, HIP_SYMBOL(g_B));   B   = (unsigned short*)p;
      hipGetSymbolAddress(&p, HIP_SYMBOL(g_C));   C   = (unsigned short*)p;
      hipGetSymbolAddress(&p, HIP_SYMBOL(g_Wq));  Wq  = (unsigned short*)p;
      hipGetSymbolAddress(&p, HIP_SYMBOL(g_Wp));  Wp  = (unsigned short*)p;
      hipGetSymbolAddress(&p, HIP_SYMBOL(g_W1));  W1  = (unsigned short*)p;
      hipGetSymbolAddress(&p, HIP_SYMBOL(g_W2));  W2  = (unsigned short*)p;
      hipGetSymbolAddress(&p, HIP_SYMBOL(g_H0));  H0 = (float*)p;
      hipGetSymbolAddress(&p, HIP_SYMBOL(g_H1));  H1 = (float*)p;
      hipGetSymbolAddress(&p, HIP_SYMBOL(g_H2));  H2 = (float*)p;
    }

    hipMemcpyAsync(X, x, (size_t)NTOK * CC * sizeof(float),
                   hipMemcpyDeviceToDevice, stream);

    // weight conversion + transpose (per launch; weights are inputs)
    for (int blk = 0; blk < 2; ++blk) {
        int base = 1 + blk * 13;
        convw_kernel<<<dim3(3072/32, 1024/32), 256, 0, stream>>>(
            P(base + 2), Wq + (size_t)blk*3072*1024, 1024, 3072);
        convw_kernel<<<dim3(1024/32, 1024/32), 256, 0, stream>>>(
            P(base + 5), Wp + (size_t)blk*1024*1024, 1024, 1024);
        convw_kernel<<<dim3(4096/32, 1024/32), 256, 0, stream>>>(
            P(base + 9), W1 + (size_t)blk*4096*1024, 1024, 4096);
        convw_kernel<<<dim3(1024/32, 4096/32), 256, 0, stream>>>(
            P(base + 11), W2 + (size_t)blk*1024*4096, 4096, 1024);
    }

    for (int blk = 0; blk < 2; ++blk) {
        int base = 1 + blk * 13;
        const float *ln1g = P(base + 0), *ln1b = P(base + 1);
        const float *qkvb = P(base + 3);
        const float *rpb  = P(base + 4);
        const float *projb = P(base + 6);
        const float *ln2g = P(base + 7), *ln2b = P(base + 8);
        const float *fc1b = P(base + 10);
        const float *fc2b = P(base + 12);
        int shifted = blk;
        const unsigned short* wq = Wq + (size_t)blk*3072*1024;
        const unsigned short* wp = Wp + (size_t)blk*1024*1024;
        const unsigned short* w1 = W1 + (size_t)blk*4096*1024;
        const unsigned short* w2 = W2 + (size_t)blk*1024*4096;

        // LN1 + window partition (+shift): X -> B (fp16, window order)
        ln_kernel<<<NTOK / 4, 256, 0, stream>>>(X, ln1g, ln1b, B, shifted, 1);
        // QKV: [12544,1024] x [3072,1024]^T -> QKV fp32   (grid 2352, GC=8)
        gemm_mfma<0><<<2352, 256, 0, stream>>>(
            B, wq, qkvb, QKV, nullptr, 3072, 1024, 0, 98, 8);
        // attention -> B (fp16, window order)
        attn_kernel<<<256 * NH, 64, 0, stream>>>(QKV, B, rpb, shifted);
        // proj + window-reverse (+unshift) + residual into X (grid 784, GC=8)
        gemm_mfma<2><<<784, 256, 0, stream>>>(
            B, wp, projb, X, nullptr, 1024, 1024, shifted, 98, 8);
        // LN2: X -> B
        ln_kernel<<<NTOK / 4, 256, 0, stream>>>(X, ln2g, ln2b, B, 0, 0);
        // FC1 + gelu -> C (fp16)  (grid 3136, GC=8)
        gemm_mfma<1><<<3136, 256, 0, stream>>>(
            B, w1, fc1b, nullptr, C, 4096, 1024, 0, 98, 8);
        // FC2 + residual into X   (grid 784, GC=2: W-set fits per-XCD L2)
        gemm_mfma<3><<<784, 256, 0, stream>>>(
            C, w2, fc2b, X, nullptr, 1024, 4096, 0, 98, 2);
    }

    // head
    pool_ln_kernel<<<64, 256, 0, stream>>>(X, P(27), P(28), H0);
    head_rowgemm<<<64, 256, 0, stream>>>(H0, P(29), P(30), H1, 1024, 512, 1);
    head_rowgemm<<<64, 256, 0, stream>>>(H1, P(31), P(32), H2, 512, 128, 1);
    head_rowgemm<<<64, 256, 0, stream>>>(H2, P(33), P(34), (float*)d_out, 128, 2, 0);
}